// Round 2
// baseline (553.916 us; speedup 1.0000x reference)
//
#include <hip/hip_runtime.h>
#include <math.h>

#define N 512
#define CS 384
#define CZ 128
#define CH 16
#define NH 12
#define PQ 4
#define PV 8

// workspace layout (float offsets)
#define OFF_Q     0          // 512*192
#define OFF_K     98304      // 512*192
#define OFF_V     196608     // 512*192
#define OFF_QRAW  294912     // 512*144
#define OFF_KVRAW 368640     // 512*432
#define OFF_QPTS  589824     // 512*144
#define OFF_KPTS  663552     // 512*144
#define OFF_VPTS  737280     // 3 planes of [hp=96][n=512] = 147456 floats (SoA x/y/z)
#define VPLANE    49152
#define OFF_A     884736     // 512*12*512 = 3145728  (A0 logits, then probs in place)
#define OFF_CAT   4030464    // 512*2112
// end = 5111808 floats

// ---------------- kernel 1: fused projections, 16-row register tile ----------------
// 256 threads: 2 rows/thread -> 4 waves/block for latency hiding.
__global__ __launch_bounds__(256) void proj_kernel(
    const float* __restrict__ s,
    const float* __restrict__ Wq,  const float* __restrict__ bq,
    const float* __restrict__ Wkv, const float* __restrict__ bkv,
    const float* __restrict__ Wqp, const float* __restrict__ bqp,
    const float* __restrict__ Wkvp,const float* __restrict__ bkvp,
    float* __restrict__ ws)
{
    __shared__ float st[16 * CS];   // 24 KB
    const int n0 = blockIdx.x * 16;
    for (int idx = threadIdx.x * 4; idx < 16 * CS; idx += 256 * 4)
        *(float4*)&st[idx] = *(const float4*)&s[n0 * CS + idx];
    __syncthreads();

    const int tc = threadIdx.x & 31;
    const int tr = threadIdx.x >> 5;       // 0..7
    const int u0 = blockIdx.y * 128 + tc * 4;
    const int r0 = tr * 2;

    const float* W; const float* bptr; int ncol, lc0;
    if (u0 < 192)      { W = Wq;   bptr = bq;   ncol = 192; lc0 = u0; }
    else if (u0 < 576) { W = Wkv;  bptr = bkv;  ncol = 384; lc0 = u0 - 192; }
    else if (u0 < 720) { W = Wqp;  bptr = bqp;  ncol = 144; lc0 = u0 - 576; }
    else               { W = Wkvp; bptr = bkvp; ncol = 432; lc0 = u0 - 720; }

    float acc[2][4];
    #pragma unroll
    for (int r = 0; r < 2; r++)
        #pragma unroll
        for (int c = 0; c < 4; c++) acc[r][c] = 0.f;

    for (int k = 0; k < CS; k += 4) {
        float4 w0 = *(const float4*)&W[(k + 0) * ncol + lc0];
        float4 w1 = *(const float4*)&W[(k + 1) * ncol + lc0];
        float4 w2 = *(const float4*)&W[(k + 2) * ncol + lc0];
        float4 w3 = *(const float4*)&W[(k + 3) * ncol + lc0];
        #pragma unroll
        for (int r = 0; r < 2; r++) {
            float4 sv = *(const float4*)&st[(r0 + r) * CS + k];
            acc[r][0] += sv.x * w0.x + sv.y * w1.x + sv.z * w2.x + sv.w * w3.x;
            acc[r][1] += sv.x * w0.y + sv.y * w1.y + sv.z * w2.y + sv.w * w3.y;
            acc[r][2] += sv.x * w0.z + sv.y * w1.z + sv.z * w2.z + sv.w * w3.z;
            acc[r][3] += sv.x * w0.w + sv.y * w1.w + sv.z * w2.w + sv.w * w3.w;
        }
    }

    #pragma unroll
    for (int c = 0; c < 4; c++) {
        const int u = u0 + c;
        const float bias = bptr[lc0 + c];
        #pragma unroll
        for (int r = 0; r < 2; r++) {
            const int n = n0 + r0 + r;
            int oidx;
            if (u < 192) oidx = OFF_Q + n * 192 + u;
            else if (u < 576) {
                int lc = u - 192, h = lc >> 5, w = lc & 31;
                oidx = (w < 16) ? OFF_K + n * 192 + h * 16 + w
                                : OFF_V + n * 192 + h * 16 + (w - 16);
            } else if (u < 720) oidx = OFF_QRAW + n * 144 + (u - 576);
            else                oidx = OFF_KVRAW + n * 432 + (u - 720);
            ws[oidx] = acc[r][c] + bias;
        }
    }
}

// ---------------- kernel 2: rigid transform of point projections ----------------
// VPTS stored as 3 SoA planes [hp][n] for vectorized reads in finish.
__global__ __launch_bounds__(192) void point_kernel(
    const float* __restrict__ t_trans, const float* __restrict__ t_rots,
    float* __restrict__ ws)
{
    const int n = blockIdx.x;
    const int t = threadIdx.x;
    __shared__ float R[9], tr[3];
    if (t < 9) R[t] = t_rots[n * 9 + t];
    if (t < 3) tr[t] = t_trans[n * 3 + t];
    __syncthreads();

    float x0, x1, x2;
    if (t < 48) {
        int idx = t;
        x0 = ws[OFF_QRAW + n * 144 + 0 * 48 + idx];
        x1 = ws[OFF_QRAW + n * 144 + 1 * 48 + idx];
        x2 = ws[OFF_QRAW + n * 144 + 2 * 48 + idx];
        int h = idx >> 2, p = idx & 3;
        int base = OFF_QPTS + ((n * NH + h) * PQ + p) * 3;
        ws[base + 0] = R[0] * x0 + R[1] * x1 + R[2] * x2 + tr[0];
        ws[base + 1] = R[3] * x0 + R[4] * x1 + R[5] * x2 + tr[1];
        ws[base + 2] = R[6] * x0 + R[7] * x1 + R[8] * x2 + tr[2];
    } else {                       // t = 48..191  -> idx 0..143 (ALL kv points)
        int idx = t - 48;
        x0 = ws[OFF_KVRAW + n * 432 + 0 * 144 + idx];
        x1 = ws[OFF_KVRAW + n * 432 + 1 * 144 + idx];
        x2 = ws[OFF_KVRAW + n * 432 + 2 * 144 + idx];
        int h = idx / 12, p = idx % 12;
        if (p < PQ) {
            int base = OFF_KPTS + ((n * NH + h) * PQ + p) * 3;
            ws[base + 0] = R[0] * x0 + R[1] * x1 + R[2] * x2 + tr[0];
            ws[base + 1] = R[3] * x0 + R[4] * x1 + R[5] * x2 + tr[1];
            ws[base + 2] = R[6] * x0 + R[7] * x1 + R[8] * x2 + tr[2];
        } else {
            int hp = h * PV + (p - PQ);
            ws[OFF_VPTS + 0 * VPLANE + hp * N + n] = R[0] * x0 + R[1] * x1 + R[2] * x2 + tr[0];
            ws[OFF_VPTS + 1 * VPLANE + hp * N + n] = R[3] * x0 + R[4] * x1 + R[5] * x2 + tr[1];
            ws[OFF_VPTS + 2 * VPLANE + hp * N + n] = R[6] * x0 + R[7] * x1 + R[8] * x2 + tr[2];
        }
    }
}

// ---------------- kernel 3: A0 = cqk*qk - 0.5*hw*d2 + mask (z-independent logits) ----------------
__global__ __launch_bounds__(192) void logitA_kernel(
    const float* __restrict__ mask, const float* __restrict__ hweights,
    float* __restrict__ ws)
{
    const int j0 = blockIdx.x * 16;
    const int i0 = blockIdx.y * 16;
    const int t = threadIdx.x;

    __shared__ float qt[16 * 200];
    __shared__ float kt[16 * 200];
    __shared__ float qpt[16 * 148];
    __shared__ float kpt[16 * 148];
    __shared__ float mi[16], mj[16];

    {
        const float* src = ws + OFF_Q + i0 * 192;
        for (int idx = t * 4; idx < 3072; idx += 768) {
            float4 v = *(const float4*)&src[idx];
            *(float4*)&qt[(idx / 192) * 200 + idx % 192] = v;
        }
    }
    {
        const float* src = ws + OFF_K + j0 * 192;
        for (int idx = t * 4; idx < 3072; idx += 768) {
            float4 v = *(const float4*)&src[idx];
            *(float4*)&kt[(idx / 192) * 200 + idx % 192] = v;
        }
    }
    {
        const float* src = ws + OFF_QPTS + i0 * 144;
        for (int idx = t * 4; idx < 2304; idx += 768) {
            float4 v = *(const float4*)&src[idx];
            *(float4*)&qpt[(idx / 144) * 148 + idx % 144] = v;
        }
    }
    {
        const float* src = ws + OFF_KPTS + j0 * 144;
        for (int idx = t * 4; idx < 2304; idx += 768) {
            float4 v = *(const float4*)&src[idx];
            *(float4*)&kpt[(idx / 144) * 148 + idx % 144] = v;
        }
    }
    if (t < 16) { mi[t] = mask[i0 + t]; mj[t] = mask[j0 + t]; }
    __syncthreads();

    const int jj = t & 15;
    const int h = t >> 4;
    const float hw = log1pf(expf(hweights[h])) * 0.13608276348795434f;
    const float cqk = 0.14433756729740643f;

    float4 kr0 = *(const float4*)&kt[jj * 200 + h * 16 + 0];
    float4 kr1 = *(const float4*)&kt[jj * 200 + h * 16 + 4];
    float4 kr2 = *(const float4*)&kt[jj * 200 + h * 16 + 8];
    float4 kr3 = *(const float4*)&kt[jj * 200 + h * 16 + 12];
    float4 kp0 = *(const float4*)&kpt[jj * 148 + h * 12 + 0];
    float4 kp1 = *(const float4*)&kpt[jj * 148 + h * 12 + 4];
    float4 kp2 = *(const float4*)&kpt[jj * 148 + h * 12 + 8];
    const float mjv = mj[jj];

    for (int ii = 0; ii < 16; ii++) {
        float4 q0 = *(const float4*)&qt[ii * 200 + h * 16 + 0];
        float4 q1 = *(const float4*)&qt[ii * 200 + h * 16 + 4];
        float4 q2 = *(const float4*)&qt[ii * 200 + h * 16 + 8];
        float4 q3 = *(const float4*)&qt[ii * 200 + h * 16 + 12];
        float qk = q0.x * kr0.x + q0.y * kr0.y + q0.z * kr0.z + q0.w * kr0.w
                 + q1.x * kr1.x + q1.y * kr1.y + q1.z * kr1.z + q1.w * kr1.w
                 + q2.x * kr2.x + q2.y * kr2.y + q2.z * kr2.z + q2.w * kr2.w
                 + q3.x * kr3.x + q3.y * kr3.y + q3.z * kr3.z + q3.w * kr3.w;
        float4 p0 = *(const float4*)&qpt[ii * 148 + h * 12 + 0];
        float4 p1 = *(const float4*)&qpt[ii * 148 + h * 12 + 4];
        float4 p2 = *(const float4*)&qpt[ii * 148 + h * 12 + 8];
        float e, d2 = 0.f;
        e = p0.x - kp0.x; d2 += e * e;  e = p0.y - kp0.y; d2 += e * e;
        e = p0.z - kp0.z; d2 += e * e;  e = p0.w - kp0.w; d2 += e * e;
        e = p1.x - kp1.x; d2 += e * e;  e = p1.y - kp1.y; d2 += e * e;
        e = p1.z - kp1.z; d2 += e * e;  e = p1.w - kp1.w; d2 += e * e;
        e = p2.x - kp2.x; d2 += e * e;  e = p2.y - kp2.y; d2 += e * e;
        e = p2.z - kp2.z; d2 += e * e;  e = p2.w - kp2.w; d2 += e * e;
        float sm = 100000.0f * (mi[ii] * mjv - 1.0f);
        ws[OFF_A + ((size_t)(i0 + ii) * NH + h) * N + j0 + jj] =
            qk * cqk - 0.5f * hw * d2 + sm;
    }
}

// ---------------- kernel 4: b = z@Wb fused with +A0 and softmax (one block per i) ----------------
// Wb read via wave-uniform addresses from global (-> s_load / SGPR operands);
// only the z tile lives in LDS, 1 ds_read_b128 per c-quad.
__global__ __launch_bounds__(512) void bsoft_kernel(
    const float* __restrict__ z, const float* __restrict__ Wb,
    const float* __restrict__ bb, float* __restrict__ ws)
{
    const int i = blockIdx.x;
    const int t = threadIdx.x;
    __shared__ float zt[128 * 132];   // 67.6 KB, stride 132 -> floor-rate b128 rows
    __shared__ float wred[8][4];      // per-wave softmax partials

    const int jj = t & 127;
    const int hgu = __builtin_amdgcn_readfirstlane(t >> 7);   // wave-uniform 0..3
    const int h0 = hgu * 3;
    const float bb0 = bb[h0], bb1 = bb[h0 + 1], bb2 = bb[h0 + 2];
    const float cb = 0.5773502691896258f;
    const float* __restrict__ Wp = Wb + h0;   // uniform base

    float lg[3][4];

    for (int T = 0; T < 4; T++) {
        __syncthreads();
        const float* zsrc = z + ((size_t)i * N + T * 128) * CZ;
        for (int idx = t * 4; idx < 16384; idx += 2048) {
            float4 v = *(const float4*)&zsrc[idx];
            *(float4*)&zt[(idx >> 7) * 132 + (idx & 127)] = v;
        }
        __syncthreads();

        float a0 = bb0, a1 = bb1, a2 = bb2;
        const float* zr = &zt[jj * 132];
        #pragma unroll
        for (int c = 0; c < CZ; c += 4) {
            float4 zq = *(const float4*)&zr[c];
            a0 += zq.x * Wp[(c + 0) * NH]     + zq.y * Wp[(c + 1) * NH]
                + zq.z * Wp[(c + 2) * NH]     + zq.w * Wp[(c + 3) * NH];
            a1 += zq.x * Wp[(c + 0) * NH + 1] + zq.y * Wp[(c + 1) * NH + 1]
                + zq.z * Wp[(c + 2) * NH + 1] + zq.w * Wp[(c + 3) * NH + 1];
            a2 += zq.x * Wp[(c + 0) * NH + 2] + zq.y * Wp[(c + 1) * NH + 2]
                + zq.z * Wp[(c + 2) * NH + 2] + zq.w * Wp[(c + 3) * NH + 2];
        }
        const float* arow = ws + OFF_A + (size_t)i * NH * N + T * 128 + jj;
        lg[0][T] = arow[(size_t)(h0 + 0) * N] + cb * a0;
        lg[1][T] = arow[(size_t)(h0 + 1) * N] + cb * a1;
        lg[2][T] = arow[(size_t)(h0 + 2) * N] + cb * a2;
    }

    // softmax over j (512 values per (i,h), spread across 128 threads x 4 T)
    const int wv = t >> 6;
    float mx[3], sm[3];
    #pragma unroll
    for (int r = 0; r < 3; r++) {
        float m = fmaxf(fmaxf(lg[r][0], lg[r][1]), fmaxf(lg[r][2], lg[r][3]));
        #pragma unroll
        for (int o = 32; o > 0; o >>= 1) m = fmaxf(m, __shfl_xor(m, o));
        mx[r] = m;
    }
    if ((t & 63) == 0) {
        wred[wv][0] = mx[0]; wred[wv][1] = mx[1]; wred[wv][2] = mx[2];
    }
    __syncthreads();
    #pragma unroll
    for (int r = 0; r < 3; r++)
        mx[r] = fmaxf(wred[hgu * 2][r], wred[hgu * 2 + 1][r]);
    __syncthreads();   // protect wred reuse
    #pragma unroll
    for (int r = 0; r < 3; r++) {
        float s = 0.f;
        #pragma unroll
        for (int T = 0; T < 4; T++) { lg[r][T] = __expf(lg[r][T] - mx[r]); s += lg[r][T]; }
        #pragma unroll
        for (int o = 32; o > 0; o >>= 1) s += __shfl_xor(s, o);
        sm[r] = s;
    }
    if ((t & 63) == 0) {
        wred[wv][0] = sm[0]; wred[wv][1] = sm[1]; wred[wv][2] = sm[2];
    }
    __syncthreads();
    #pragma unroll
    for (int r = 0; r < 3; r++) {
        float inv = 1.0f / (wred[hgu * 2][r] + wred[hgu * 2 + 1][r]);
        float* prow = ws + OFF_A + ((size_t)i * NH + h0 + r) * N + jj;
        #pragma unroll
        for (int T = 0; T < 4; T++)
            prow[T * 128] = lg[r][T] * inv;
    }
}

// ---------------- kernel 5: o / o_pt / o_pair, register-tiled, float4 streams ----------------
// 384 threads: [0,192) o_pair (2 heads x 4 c each), [192,240) o (h,c4),
// [240,336) o_pt (h,p), rest idle. Barrier every 64 j keeps waves L1-aligned.
__global__ __launch_bounds__(384) void finish_kernel(
    const float* __restrict__ z, const float* __restrict__ t_trans,
    const float* __restrict__ t_rots, const float* __restrict__ ws_c,
    float* __restrict__ ws)
{
    const int i = blockIdx.x;
    const int t = threadIdx.x;
    __shared__ float a_s[12 * 520];

    {
        const float* src = ws_c + OFF_A + (size_t)i * (NH * N);
        for (int idx = t * 4; idx < NH * N; idx += 384 * 4) {
            float4 v = *(const float4*)&src[idx];
            int h = idx >> 9, j = idx & 511;
            *(float4*)&a_s[h * 520 + j] = v;
        }
    }
    __syncthreads();

    float* cat = ws + OFF_CAT + (size_t)i * 2112;

    // persistent accumulators
    float4 accA = {0,0,0,0}, accB = {0,0,0,0};   // o_pair (h, h+6)
    float4 accO = {0,0,0,0};                     // o
    float g0 = 0.f, g1 = 0.f, g2 = 0.f;          // o_pt

    const int cg = t & 31;
    const int hp6 = t >> 5;                      // o_pair head group 0..5
    const float* zb = z + (size_t)i * N * CZ + cg * 4;
    const float* ahA = a_s + hp6 * 520;
    const float* ahB = a_s + (hp6 + 6) * 520;

    const int uo = t - 192;                      // o: 0..47
    const int ho = uo >> 2, cgo = uo & 3;
    const float* ahO = a_s + ho * 520;

    const int up = t - 240;                      // o_pt: 0..95 (= hp)
    const float* ahP = a_s + (up >> 3) * 520;
    const float* vx = ws_c + OFF_VPTS + 0 * VPLANE + up * N;
    const float* vy = ws_c + OFF_VPTS + 1 * VPLANE + up * N;
    const float* vz = ws_c + OFF_VPTS + 2 * VPLANE + up * N;

    for (int jt = 0; jt < N; jt += 64) {
        if (t < 192) {                 // o_pair: 2 heads x 4 channels
            #pragma unroll 4
            for (int jo = 0; jo < 64; jo += 4) {
                const int j = jt + jo;
                float4 aA = *(const float4*)&ahA[j];
                float4 aB = *(const float4*)&ahB[j];
                float4 z0 = *(const float4*)&zb[(size_t)(j + 0) * CZ];
                float4 z1 = *(const float4*)&zb[(size_t)(j + 1) * CZ];
                float4 z2 = *(const float4*)&zb[(size_t)(j + 2) * CZ];
                float4 z3 = *(const float4*)&zb[(size_t)(j + 3) * CZ];
                accA.x += aA.x * z0.x + aA.y * z1.x + aA.z * z2.x + aA.w * z3.x;
                accA.y += aA.x * z0.y + aA.y * z1.y + aA.z * z2.y + aA.w * z3.y;
                accA.z += aA.x * z0.z + aA.y * z1.z + aA.z * z2.z + aA.w * z3.z;
                accA.w += aA.x * z0.w + aA.y * z1.w + aA.z * z2.w + aA.w * z3.w;
                accB.x += aB.x * z0.x + aB.y * z1.x + aB.z * z2.x + aB.w * z3.x;
                accB.y += aB.x * z0.y + aB.y * z1.y + aB.z * z2.y + aB.w * z3.y;
                accB.z += aB.x * z0.z + aB.y * z1.z + aB.z * z2.z + aB.w * z3.z;
                accB.w += aB.x * z0.w + aB.y * z1.w + aB.z * z2.w + aB.w * z3.w;
            }
        } else if (t < 240) {          // o: (h, c4)
            #pragma unroll 4
            for (int jo = 0; jo < 64; jo += 4) {
                const int j = jt + jo;
                float4 a4 = *(const float4*)&ahO[j];
                float4 v0 = *(const float4*)&ws_c[OFF_V + (j + 0) * 192 + ho * 16 + cgo * 4];
                float4 v1 = *(const float4*)&ws_c[OFF_V + (j + 1) * 192 + ho * 16 + cgo * 4];
                float4 v2 = *(const float4*)&ws_c[OFF_V + (j + 2) * 192 + ho * 16 + cgo * 4];
                float4 v3 = *(const float4*)&ws_c[OFF_V + (j + 3) * 192 + ho * 16 + cgo * 4];
                accO.x += a4.x * v0.x + a4.y * v1.x + a4.z * v2.x + a4.w * v3.x;
                accO.y += a4.x * v0.y + a4.y * v1.y + a4.z * v2.y + a4.w * v3.y;
                accO.z += a4.x * v0.z + a4.y * v1.z + a4.z * v2.z + a4.w * v3.z;
                accO.w += a4.x * v0.w + a4.y * v1.w + a4.z * v2.w + a4.w * v3.w;
            }
        } else if (t < 336) {          // o_pt: (h, p), SoA planes
            #pragma unroll 4
            for (int jo = 0; jo < 64; jo += 4) {
                const int j = jt + jo;
                float4 a4 = *(const float4*)&ahP[j];
                float4 x4 = *(const float4*)&vx[j];
                float4 y4 = *(const float4*)&vy[j];
                float4 z4 = *(const float4*)&vz[j];
                g0 += a4.x * x4.x + a4.y * x4.y + a4.z * x4.z + a4.w * x4.w;
                g1 += a4.x * y4.x + a4.y * y4.y + a4.z * y4.z + a4.w * y4.w;
                g2 += a4.x * z4.x + a4.y * z4.y + a4.z * z4.z + a4.w * z4.w;
            }
        }
        __syncthreads();
    }

    if (t < 192) {
        *(float4*)&cat[576 + hp6 * CZ + cg * 4]       = accA;
        *(float4*)&cat[576 + (hp6 + 6) * CZ + cg * 4] = accB;
    } else if (t < 240) {
        *(float4*)&cat[ho * 16 + cgo * 4] = accO;
    } else if (t < 336) {
        float R[9], ti[3];
        #pragma unroll
        for (int x = 0; x < 9; x++) R[x] = t_rots[i * 9 + x];
        #pragma unroll
        for (int x = 0; x < 3; x++) ti[x] = t_trans[i * 3 + x];
        g0 -= ti[0]; g1 -= ti[1]; g2 -= ti[2];
        float l0 = R[0] * g0 + R[3] * g1 + R[6] * g2;
        float l1 = R[1] * g0 + R[4] * g1 + R[7] * g2;
        float l2 = R[2] * g0 + R[5] * g1 + R[8] * g2;
        float nrm = sqrtf(l0 * l0 + l1 * l1 + l2 * l2 + 1e-8f);
        cat[192 + up] = l0;
        cat[288 + up] = l1;
        cat[384 + up] = l2;
        cat[480 + up] = nrm;
    }
}

// ---------------- kernel 6a: init out with bias ----------------
__global__ __launch_bounds__(384) void init_out_kernel(
    const float* __restrict__ bout, float* __restrict__ out)
{
    out[(size_t)blockIdx.x * 384 + threadIdx.x] = bout[threadIdx.x];
}

// ---------------- kernel 6b: out += cat @ Wout (k-split, atomic) ----------------
__global__ __launch_bounds__(384) void out_kernel(
    const float* __restrict__ Wout, const float* __restrict__ ws,
    float* __restrict__ out)
{
    const int rt = blockIdx.x;
    const int kc = blockIdx.y;
    const int t = threadIdx.x;
    __shared__ float ct[16 * 264];
    for (int idx = t * 4; idx < 16 * 264; idx += 384 * 4) {
        int rr = idx / 264, kk = idx % 264;
        *(float4*)&ct[idx] =
            *(const float4*)&ws[OFF_CAT + (size_t)(rt * 16 + rr) * 2112 + kc * 264 + kk];
    }
    __syncthreads();
    const int cq = t % 96, rg = t / 96;
    const int c0 = cq * 4;
    float acc[4][4] = {};
    const float* Wp = Wout + (size_t)kc * 264 * 384 + c0;
    for (int kk = 0; kk < 264; kk += 4) {
        float4 w0 = *(const float4*)&Wp[(size_t)(kk + 0) * 384];
        float4 w1 = *(const float4*)&Wp[(size_t)(kk + 1) * 384];
        float4 w2 = *(const float4*)&Wp[(size_t)(kk + 2) * 384];
        float4 w3 = *(const float4*)&Wp[(size_t)(kk + 3) * 384];
        #pragma unroll
        for (int r = 0; r < 4; r++) {
            float4 sv = *(const float4*)&ct[(rg * 4 + r) * 264 + kk];
            acc[r][0] += sv.x * w0.x + sv.y * w1.x + sv.z * w2.x + sv.w * w3.x;
            acc[r][1] += sv.x * w0.y + sv.y * w1.y + sv.z * w2.y + sv.w * w3.y;
            acc[r][2] += sv.x * w0.z + sv.y * w1.z + sv.z * w2.z + sv.w * w3.z;
            acc[r][3] += sv.x * w0.w + sv.y * w1.w + sv.z * w2.w + sv.w * w3.w;
        }
    }
    #pragma unroll
    for (int r = 0; r < 4; r++) {
        float* op = out + (size_t)(rt * 16 + rg * 4 + r) * 384 + c0;
        atomicAdd(&op[0], acc[r][0]);
        atomicAdd(&op[1], acc[r][1]);
        atomicAdd(&op[2], acc[r][2]);
        atomicAdd(&op[3], acc[r][3]);
    }
}

extern "C" void kernel_launch(void* const* d_in, const int* in_sizes, int n_in,
                              void* d_out, int out_size, void* d_ws, size_t ws_size,
                              hipStream_t stream) {
    const float* s       = (const float*)d_in[0];
    const float* z       = (const float*)d_in[1];
    const float* t_trans = (const float*)d_in[2];
    const float* t_rots  = (const float*)d_in[3];
    const float* mask    = (const float*)d_in[4];
    const float* Wq      = (const float*)d_in[5];
    const float* bq      = (const float*)d_in[6];
    const float* Wkv     = (const float*)d_in[7];
    const float* bkv     = (const float*)d_in[8];
    const float* Wqp     = (const float*)d_in[9];
    const float* bqp     = (const float*)d_in[10];
    const float* Wkvp    = (const float*)d_in[11];
    const float* bkvp    = (const float*)d_in[12];
    const float* Wb      = (const float*)d_in[13];
    const float* bb      = (const float*)d_in[14];
    const float* hweights= (const float*)d_in[15];
    const float* Wout    = (const float*)d_in[16];
    const float* bout    = (const float*)d_in[17];
    float* ws  = (float*)d_ws;
    float* out = (float*)d_out;

    init_out_kernel<<<512, 384, 0, stream>>>(bout, out);
    proj_kernel<<<dim3(32, 9), 256, 0, stream>>>(s, Wq, bq, Wkv, bkv, Wqp, bqp, Wkvp, bkvp, ws);
    point_kernel<<<512, 192, 0, stream>>>(t_trans, t_rots, ws);
    logitA_kernel<<<dim3(32, 32), 192, 0, stream>>>(mask, hweights, ws);
    bsoft_kernel<<<512, 512, 0, stream>>>(z, Wb, bb, ws);
    finish_kernel<<<512, 384, 0, stream>>>(z, t_trans, t_rots, ws, ws);
    out_kernel<<<dim3(32, 8), 384, 0, stream>>>(Wout, ws, out);
}

// Round 4
// 514.606 us; speedup vs baseline: 1.0764x; 1.0764x over previous
//
#include <hip/hip_runtime.h>
#include <math.h>

#define N 512
#define CS 384
#define CZ 128
#define CH 16
#define NH 12
#define PQ 4
#define PV 8

// workspace layout (float offsets)
#define OFF_Q     0          // 512*192
#define OFF_K     98304      // 512*192
#define OFF_V     196608     // 512*192
#define OFF_QRAW  294912     // 512*144
#define OFF_KVRAW 368640     // 512*432
#define OFF_QPTS  589824     // 512*144
#define OFF_KPTS  663552     // 512*144
#define OFF_VPTS  737280     // 512*288 AoS: [n][h*PV+p][xyz]
#define OFF_A     884736     // 512*12*512 = 3145728  (A0 logits, then probs in place)
#define OFF_CAT   4030464    // 512*2112
// end = 5111808 floats

// ---------------- kernel 1: fused projections, 16-row register tile ----------------
// 256 threads: 2 rows/thread -> 4 waves/block for latency hiding.
__global__ __launch_bounds__(256) void proj_kernel(
    const float* __restrict__ s,
    const float* __restrict__ Wq,  const float* __restrict__ bq,
    const float* __restrict__ Wkv, const float* __restrict__ bkv,
    const float* __restrict__ Wqp, const float* __restrict__ bqp,
    const float* __restrict__ Wkvp,const float* __restrict__ bkvp,
    float* __restrict__ ws)
{
    __shared__ float st[16 * CS];   // 24 KB
    const int n0 = blockIdx.x * 16;
    for (int idx = threadIdx.x * 4; idx < 16 * CS; idx += 256 * 4)
        *(float4*)&st[idx] = *(const float4*)&s[n0 * CS + idx];
    __syncthreads();

    const int tc = threadIdx.x & 31;
    const int tr = threadIdx.x >> 5;       // 0..7
    const int u0 = blockIdx.y * 128 + tc * 4;
    const int r0 = tr * 2;

    const float* W; const float* bptr; int ncol, lc0;
    if (u0 < 192)      { W = Wq;   bptr = bq;   ncol = 192; lc0 = u0; }
    else if (u0 < 576) { W = Wkv;  bptr = bkv;  ncol = 384; lc0 = u0 - 192; }
    else if (u0 < 720) { W = Wqp;  bptr = bqp;  ncol = 144; lc0 = u0 - 576; }
    else               { W = Wkvp; bptr = bkvp; ncol = 432; lc0 = u0 - 720; }

    float acc[2][4];
    #pragma unroll
    for (int r = 0; r < 2; r++)
        #pragma unroll
        for (int c = 0; c < 4; c++) acc[r][c] = 0.f;

    for (int k = 0; k < CS; k += 4) {
        float4 w0 = *(const float4*)&W[(k + 0) * ncol + lc0];
        float4 w1 = *(const float4*)&W[(k + 1) * ncol + lc0];
        float4 w2 = *(const float4*)&W[(k + 2) * ncol + lc0];
        float4 w3 = *(const float4*)&W[(k + 3) * ncol + lc0];
        #pragma unroll
        for (int r = 0; r < 2; r++) {
            float4 sv = *(const float4*)&st[(r0 + r) * CS + k];
            acc[r][0] += sv.x * w0.x + sv.y * w1.x + sv.z * w2.x + sv.w * w3.x;
            acc[r][1] += sv.x * w0.y + sv.y * w1.y + sv.z * w2.y + sv.w * w3.y;
            acc[r][2] += sv.x * w0.z + sv.y * w1.z + sv.z * w2.z + sv.w * w3.z;
            acc[r][3] += sv.x * w0.w + sv.y * w1.w + sv.z * w2.w + sv.w * w3.w;
        }
    }

    #pragma unroll
    for (int c = 0; c < 4; c++) {
        const int u = u0 + c;
        const float bias = bptr[lc0 + c];
        #pragma unroll
        for (int r = 0; r < 2; r++) {
            const int n = n0 + r0 + r;
            int oidx;
            if (u < 192) oidx = OFF_Q + n * 192 + u;
            else if (u < 576) {
                int lc = u - 192, h = lc >> 5, w = lc & 31;
                oidx = (w < 16) ? OFF_K + n * 192 + h * 16 + w
                                : OFF_V + n * 192 + h * 16 + (w - 16);
            } else if (u < 720) oidx = OFF_QRAW + n * 144 + (u - 576);
            else                oidx = OFF_KVRAW + n * 432 + (u - 720);
            ws[oidx] = acc[r][c] + bias;
        }
    }
}

// ---------------- kernel 2: rigid transform of point projections (AoS VPTS) ----------------
__global__ __launch_bounds__(192) void point_kernel(
    const float* __restrict__ t_trans, const float* __restrict__ t_rots,
    float* __restrict__ ws)
{
    const int n = blockIdx.x;
    const int t = threadIdx.x;
    __shared__ float R[9], tr[3];
    if (t < 9) R[t] = t_rots[n * 9 + t];
    if (t < 3) tr[t] = t_trans[n * 3 + t];
    __syncthreads();

    float x0, x1, x2;
    int base;
    if (t < 48) {
        int idx = t;
        x0 = ws[OFF_QRAW + n * 144 + 0 * 48 + idx];
        x1 = ws[OFF_QRAW + n * 144 + 1 * 48 + idx];
        x2 = ws[OFF_QRAW + n * 144 + 2 * 48 + idx];
        int h = idx >> 2, p = idx & 3;
        base = OFF_QPTS + ((n * NH + h) * PQ + p) * 3;
    } else {                       // t = 48..191 -> idx 0..143 (ALL kv points)
        int idx = t - 48;
        x0 = ws[OFF_KVRAW + n * 432 + 0 * 144 + idx];
        x1 = ws[OFF_KVRAW + n * 432 + 1 * 144 + idx];
        x2 = ws[OFF_KVRAW + n * 432 + 2 * 144 + idx];
        int h = idx / 12, p = idx % 12;
        if (p < PQ) base = OFF_KPTS + ((n * NH + h) * PQ + p) * 3;
        else        base = OFF_VPTS + (n * NH * PV + h * PV + (p - PQ)) * 3;
    }
    ws[base + 0] = R[0] * x0 + R[1] * x1 + R[2] * x2 + tr[0];
    ws[base + 1] = R[3] * x0 + R[4] * x1 + R[5] * x2 + tr[1];
    ws[base + 2] = R[6] * x0 + R[7] * x1 + R[8] * x2 + tr[2];
}

// ---------------- kernel 3: A0 = cqk*qk - 0.5*hw*d2 + mask ----------------
__global__ __launch_bounds__(192) void logitA_kernel(
    const float* __restrict__ mask, const float* __restrict__ hweights,
    float* __restrict__ ws)
{
    const int j0 = blockIdx.x * 16;
    const int i0 = blockIdx.y * 16;
    const int t = threadIdx.x;

    __shared__ float qt[16 * 200];
    __shared__ float kt[16 * 200];
    __shared__ float qpt[16 * 148];
    __shared__ float kpt[16 * 148];
    __shared__ float mi[16], mj[16];

    {
        const float* src = ws + OFF_Q + i0 * 192;
        for (int idx = t * 4; idx < 3072; idx += 768) {
            float4 v = *(const float4*)&src[idx];
            *(float4*)&qt[(idx / 192) * 200 + idx % 192] = v;
        }
    }
    {
        const float* src = ws + OFF_K + j0 * 192;
        for (int idx = t * 4; idx < 3072; idx += 768) {
            float4 v = *(const float4*)&src[idx];
            *(float4*)&kt[(idx / 192) * 200 + idx % 192] = v;
        }
    }
    {
        const float* src = ws + OFF_QPTS + i0 * 144;
        for (int idx = t * 4; idx < 2304; idx += 768) {
            float4 v = *(const float4*)&src[idx];
            *(float4*)&qpt[(idx / 144) * 148 + idx % 144] = v;
        }
    }
    {
        const float* src = ws + OFF_KPTS + j0 * 144;
        for (int idx = t * 4; idx < 2304; idx += 768) {
            float4 v = *(const float4*)&src[idx];
            *(float4*)&kpt[(idx / 144) * 148 + idx % 144] = v;
        }
    }
    if (t < 16) { mi[t] = mask[i0 + t]; mj[t] = mask[j0 + t]; }
    __syncthreads();

    const int jj = t & 15;
    const int h = t >> 4;
    const float hw = log1pf(expf(hweights[h])) * 0.13608276348795434f;
    const float cqk = 0.14433756729740643f;

    float4 kr0 = *(const float4*)&kt[jj * 200 + h * 16 + 0];
    float4 kr1 = *(const float4*)&kt[jj * 200 + h * 16 + 4];
    float4 kr2 = *(const float4*)&kt[jj * 200 + h * 16 + 8];
    float4 kr3 = *(const float4*)&kt[jj * 200 + h * 16 + 12];
    float4 kp0 = *(const float4*)&kpt[jj * 148 + h * 12 + 0];
    float4 kp1 = *(const float4*)&kpt[jj * 148 + h * 12 + 4];
    float4 kp2 = *(const float4*)&kpt[jj * 148 + h * 12 + 8];
    const float mjv = mj[jj];

    for (int ii = 0; ii < 16; ii++) {
        float4 q0 = *(const float4*)&qt[ii * 200 + h * 16 + 0];
        float4 q1 = *(const float4*)&qt[ii * 200 + h * 16 + 4];
        float4 q2 = *(const float4*)&qt[ii * 200 + h * 16 + 8];
        float4 q3 = *(const float4*)&qt[ii * 200 + h * 16 + 12];
        float qk = q0.x * kr0.x + q0.y * kr0.y + q0.z * kr0.z + q0.w * kr0.w
                 + q1.x * kr1.x + q1.y * kr1.y + q1.z * kr1.z + q1.w * kr1.w
                 + q2.x * kr2.x + q2.y * kr2.y + q2.z * kr2.z + q2.w * kr2.w
                 + q3.x * kr3.x + q3.y * kr3.y + q3.z * kr3.z + q3.w * kr3.w;
        float4 p0 = *(const float4*)&qpt[ii * 148 + h * 12 + 0];
        float4 p1 = *(const float4*)&qpt[ii * 148 + h * 12 + 4];
        float4 p2 = *(const float4*)&qpt[ii * 148 + h * 12 + 8];
        float e, d2 = 0.f;
        e = p0.x - kp0.x; d2 += e * e;  e = p0.y - kp0.y; d2 += e * e;
        e = p0.z - kp0.z; d2 += e * e;  e = p0.w - kp0.w; d2 += e * e;
        e = p1.x - kp1.x; d2 += e * e;  e = p1.y - kp1.y; d2 += e * e;
        e = p1.z - kp1.z; d2 += e * e;  e = p1.w - kp1.w; d2 += e * e;
        e = p2.x - kp2.x; d2 += e * e;  e = p2.y - kp2.y; d2 += e * e;
        e = p2.z - kp2.z; d2 += e * e;  e = p2.w - kp2.w; d2 += e * e;
        float sm = 100000.0f * (mi[ii] * mjv - 1.0f);
        ws[OFF_A + ((size_t)(i0 + ii) * NH + h) * N + j0 + jj] =
            qk * cqk - 0.5f * hw * d2 + sm;
    }
}

// ---------------- kernel 4: b = z@Wb fused with +A0 and softmax (one block per i) ----------------
__global__ __launch_bounds__(512) void bsoft_kernel(
    const float* __restrict__ z, const float* __restrict__ Wb,
    const float* __restrict__ bb, float* __restrict__ ws)
{
    const int i = blockIdx.x;
    const int t = threadIdx.x;
    __shared__ float zt[128 * 132];   // 67.6 KB
    __shared__ float wred[8][4];      // per-wave softmax partials

    const int jj = t & 127;
    const int hgu = __builtin_amdgcn_readfirstlane(t >> 7);   // wave-uniform 0..3
    const int h0 = hgu * 3;
    const float bb0 = bb[h0], bb1 = bb[h0 + 1], bb2 = bb[h0 + 2];
    const float cb = 0.5773502691896258f;
    const float* __restrict__ Wp = Wb + h0;   // uniform base

    float lg[3][4];

    for (int T = 0; T < 4; T++) {
        __syncthreads();
        const float* zsrc = z + ((size_t)i * N + T * 128) * CZ;
        for (int idx = t * 4; idx < 16384; idx += 2048) {
            float4 v = *(const float4*)&zsrc[idx];
            *(float4*)&zt[(idx >> 7) * 132 + (idx & 127)] = v;
        }
        __syncthreads();

        float a0 = bb0, a1 = bb1, a2 = bb2;
        const float* zr = &zt[jj * 132];
        #pragma unroll
        for (int c = 0; c < CZ; c += 4) {
            float4 zq = *(const float4*)&zr[c];
            a0 += zq.x * Wp[(c + 0) * NH]     + zq.y * Wp[(c + 1) * NH]
                + zq.z * Wp[(c + 2) * NH]     + zq.w * Wp[(c + 3) * NH];
            a1 += zq.x * Wp[(c + 0) * NH + 1] + zq.y * Wp[(c + 1) * NH + 1]
                + zq.z * Wp[(c + 2) * NH + 1] + zq.w * Wp[(c + 3) * NH + 1];
            a2 += zq.x * Wp[(c + 0) * NH + 2] + zq.y * Wp[(c + 1) * NH + 2]
                + zq.z * Wp[(c + 2) * NH + 2] + zq.w * Wp[(c + 3) * NH + 2];
        }
        const float* arow = ws + OFF_A + (size_t)i * NH * N + T * 128 + jj;
        lg[0][T] = arow[(size_t)(h0 + 0) * N] + cb * a0;
        lg[1][T] = arow[(size_t)(h0 + 1) * N] + cb * a1;
        lg[2][T] = arow[(size_t)(h0 + 2) * N] + cb * a2;
    }

    const int wv = t >> 6;
    float mx[3], sm[3];
    #pragma unroll
    for (int r = 0; r < 3; r++) {
        float m = fmaxf(fmaxf(lg[r][0], lg[r][1]), fmaxf(lg[r][2], lg[r][3]));
        #pragma unroll
        for (int o = 32; o > 0; o >>= 1) m = fmaxf(m, __shfl_xor(m, o));
        mx[r] = m;
    }
    if ((t & 63) == 0) {
        wred[wv][0] = mx[0]; wred[wv][1] = mx[1]; wred[wv][2] = mx[2];
    }
    __syncthreads();
    #pragma unroll
    for (int r = 0; r < 3; r++)
        mx[r] = fmaxf(wred[hgu * 2][r], wred[hgu * 2 + 1][r]);
    __syncthreads();
    #pragma unroll
    for (int r = 0; r < 3; r++) {
        float s = 0.f;
        #pragma unroll
        for (int T = 0; T < 4; T++) { lg[r][T] = __expf(lg[r][T] - mx[r]); s += lg[r][T]; }
        #pragma unroll
        for (int o = 32; o > 0; o >>= 1) s += __shfl_xor(s, o);
        sm[r] = s;
    }
    if ((t & 63) == 0) {
        wred[wv][0] = sm[0]; wred[wv][1] = sm[1]; wred[wv][2] = sm[2];
    }
    __syncthreads();
    #pragma unroll
    for (int r = 0; r < 3; r++) {
        float inv = 1.0f / (wred[hgu * 2][r] + wred[hgu * 2 + 1][r]);
        float* prow = ws + OFF_A + ((size_t)i * NH + h0 + r) * N + jj;
        #pragma unroll
        for (int T = 0; T < 4; T++)
            prow[T * 128] = lg[r][T] * inv;
    }
}

// ---------------- kernel 5: o / o_pt / o_pair — free-running waves, single barrier ----------------
// 512 threads: [0,192) o_pair vectorized (c-quad x head-pair), [192,384) o scalar,
// [384,480) o_pt scalar AoS, rest idle. No per-tile barriers.
__global__ __launch_bounds__(512) void finish_kernel(
    const float* __restrict__ z, const float* __restrict__ t_trans,
    const float* __restrict__ t_rots, const float* __restrict__ ws_c,
    float* __restrict__ ws)
{
    const int i = blockIdx.x;
    const int t = threadIdx.x;
    __shared__ float a_s[12 * 520];

    {
        const float* src = ws_c + OFF_A + (size_t)i * (NH * N);
        for (int idx = t * 4; idx < NH * N; idx += 512 * 4) {
            float4 v = *(const float4*)&src[idx];
            int h = idx >> 9, j = idx & 511;
            *(float4*)&a_s[h * 520 + j] = v;
        }
    }
    __syncthreads();

    float* cat = ws + OFF_CAT + (size_t)i * 2112;

    if (t < 192) {          // o_pair: cg = c-quad 0..31, hs = 0..5 handles heads hs, hs+6
        const int cg = t & 31;
        const int hs = t >> 5;
        const float* zb = z + (size_t)i * N * CZ + cg * 4;
        const float* ahA = a_s + hs * 520;
        const float* ahB = a_s + (hs + 6) * 520;
        float4 accA = {0,0,0,0}, accB = {0,0,0,0};
        #pragma unroll 4
        for (int j = 0; j < N; j += 4) {
            float4 aA = *(const float4*)&ahA[j];
            float4 aB = *(const float4*)&ahB[j];
            float4 z0 = *(const float4*)&zb[(size_t)(j + 0) * CZ];
            float4 z1 = *(const float4*)&zb[(size_t)(j + 1) * CZ];
            float4 z2 = *(const float4*)&zb[(size_t)(j + 2) * CZ];
            float4 z3 = *(const float4*)&zb[(size_t)(j + 3) * CZ];
            accA.x += aA.x * z0.x + aA.y * z1.x + aA.z * z2.x + aA.w * z3.x;
            accA.y += aA.x * z0.y + aA.y * z1.y + aA.z * z2.y + aA.w * z3.y;
            accA.z += aA.x * z0.z + aA.y * z1.z + aA.z * z2.z + aA.w * z3.z;
            accA.w += aA.x * z0.w + aA.y * z1.w + aA.z * z2.w + aA.w * z3.w;
            accB.x += aB.x * z0.x + aB.y * z1.x + aB.z * z2.x + aB.w * z3.x;
            accB.y += aB.x * z0.y + aB.y * z1.y + aB.z * z2.y + aB.w * z3.y;
            accB.z += aB.x * z0.z + aB.y * z1.z + aB.z * z2.z + aB.w * z3.z;
            accB.w += aB.x * z0.w + aB.y * z1.w + aB.z * z2.w + aB.w * z3.w;
        }
        *(float4*)&cat[576 + hs * CZ + cg * 4]       = accA;
        *(float4*)&cat[576 + (hs + 6) * CZ + cg * 4] = accB;
    } else if (t < 384) {   // o
        const int u = t - 192, h = u >> 4, cc = u & 15;
        const float* vcol = ws_c + OFF_V + h * 16 + cc;
        const float* ah = a_s + h * 520;
        float acc = 0.f;
        #pragma unroll 8
        for (int j = 0; j < N; j++)
            acc += ah[j] * vcol[j * 192];
        cat[h * 16 + cc] = acc;
    } else if (t < 480) {   // o_pt (AoS)
        const int up = t - 384, h = up >> 3, p = up & 7;
        const float* vp = ws_c + OFF_VPTS + (h * PV + p) * 3;
        const float* ah = a_s + h * 520;
        float g0 = 0.f, g1 = 0.f, g2 = 0.f;
        #pragma unroll 4
        for (int j = 0; j < N; j++) {
            float av = ah[j];
            const float* vpj = vp + (size_t)j * (NH * PV * 3);
            g0 += av * vpj[0]; g1 += av * vpj[1]; g2 += av * vpj[2];
        }
        float R[9], ti[3];
        #pragma unroll
        for (int x = 0; x < 9; x++) R[x] = t_rots[i * 9 + x];
        #pragma unroll
        for (int x = 0; x < 3; x++) ti[x] = t_trans[i * 3 + x];
        g0 -= ti[0]; g1 -= ti[1]; g2 -= ti[2];
        float l0 = R[0] * g0 + R[3] * g1 + R[6] * g2;
        float l1 = R[1] * g0 + R[4] * g1 + R[7] * g2;
        float l2 = R[2] * g0 + R[5] * g1 + R[8] * g2;
        float nrm = sqrtf(l0 * l0 + l1 * l1 + l2 * l2 + 1e-8f);
        int e = h * PV + p;
        cat[192 + e] = l0;
        cat[288 + e] = l1;
        cat[384 + e] = l2;
        cat[480 + e] = nrm;
    }
}

// ---------------- kernel 6a: init out with bias ----------------
__global__ __launch_bounds__(384) void init_out_kernel(
    const float* __restrict__ bout, float* __restrict__ out)
{
    out[(size_t)blockIdx.x * 384 + threadIdx.x] = bout[threadIdx.x];
}

// ---------------- kernel 6b: out += cat @ Wout (k-split, atomic) ----------------
__global__ __launch_bounds__(384) void out_kernel(
    const float* __restrict__ Wout, const float* __restrict__ ws,
    float* __restrict__ out)
{
    const int rt = blockIdx.x;
    const int kc = blockIdx.y;
    const int t = threadIdx.x;
    __shared__ float ct[16 * 264];
    for (int idx = t * 4; idx < 16 * 264; idx += 384 * 4) {
        int rr = idx / 264, kk = idx % 264;
        *(float4*)&ct[idx] =
            *(const float4*)&ws[OFF_CAT + (size_t)(rt * 16 + rr) * 2112 + kc * 264 + kk];
    }
    __syncthreads();
    const int cq = t % 96, rg = t / 96;
    const int c0 = cq * 4;
    float acc[4][4] = {};
    const float* Wp = Wout + (size_t)kc * 264 * 384 + c0;
    for (int kk = 0; kk < 264; kk += 4) {
        float4 w0 = *(const float4*)&Wp[(size_t)(kk + 0) * 384];
        float4 w1 = *(const float4*)&Wp[(size_t)(kk + 1) * 384];
        float4 w2 = *(const float4*)&Wp[(size_t)(kk + 2) * 384];
        float4 w3 = *(const float4*)&Wp[(size_t)(kk + 3) * 384];
        #pragma unroll
        for (int r = 0; r < 4; r++) {
            float4 sv = *(const float4*)&ct[(rg * 4 + r) * 264 + kk];
            acc[r][0] += sv.x * w0.x + sv.y * w1.x + sv.z * w2.x + sv.w * w3.x;
            acc[r][1] += sv.x * w0.y + sv.y * w1.y + sv.z * w2.y + sv.w * w3.y;
            acc[r][2] += sv.x * w0.z + sv.y * w1.z + sv.z * w2.z + sv.w * w3.z;
            acc[r][3] += sv.x * w0.w + sv.y * w1.w + sv.z * w2.w + sv.w * w3.w;
        }
    }
    #pragma unroll
    for (int r = 0; r < 4; r++) {
        float* op = out + (size_t)(rt * 16 + rg * 4 + r) * 384 + c0;
        atomicAdd(&op[0], acc[r][0]);
        atomicAdd(&op[1], acc[r][1]);
        atomicAdd(&op[2], acc[r][2]);
        atomicAdd(&op[3], acc[r][3]);
    }
}

extern "C" void kernel_launch(void* const* d_in, const int* in_sizes, int n_in,
                              void* d_out, int out_size, void* d_ws, size_t ws_size,
                              hipStream_t stream) {
    const float* s       = (const float*)d_in[0];
    const float* z       = (const float*)d_in[1];
    const float* t_trans = (const float*)d_in[2];
    const float* t_rots  = (const float*)d_in[3];
    const float* mask    = (const float*)d_in[4];
    const float* Wq      = (const float*)d_in[5];
    const float* bq      = (const float*)d_in[6];
    const float* Wkv     = (const float*)d_in[7];
    const float* bkv     = (const float*)d_in[8];
    const float* Wqp     = (const float*)d_in[9];
    const float* bqp     = (const float*)d_in[10];
    const float* Wkvp    = (const float*)d_in[11];
    const float* bkvp    = (const float*)d_in[12];
    const float* Wb      = (const float*)d_in[13];
    const float* bb      = (const float*)d_in[14];
    const float* hweights= (const float*)d_in[15];
    const float* Wout    = (const float*)d_in[16];
    const float* bout    = (const float*)d_in[17];
    float* ws  = (float*)d_ws;
    float* out = (float*)d_out;

    init_out_kernel<<<512, 384, 0, stream>>>(bout, out);
    proj_kernel<<<dim3(32, 9), 256, 0, stream>>>(s, Wq, bq, Wkv, bkv, Wqp, bqp, Wkvp, bkvp, ws);
    point_kernel<<<512, 192, 0, stream>>>(t_trans, t_rots, ws);
    logitA_kernel<<<dim3(32, 32), 192, 0, stream>>>(mask, hweights, ws);
    bsoft_kernel<<<512, 512, 0, stream>>>(z, Wb, bb, ws);
    finish_kernel<<<512, 512, 0, stream>>>(z, t_trans, t_rots, ws, ws);
    out_kernel<<<dim3(32, 8), 384, 0, stream>>>(Wout, ws, out);
}

// Round 5
// 443.664 us; speedup vs baseline: 1.2485x; 1.1599x over previous
//
#include <hip/hip_runtime.h>
#include <math.h>

#define N 512
#define CS 384
#define CZ 128
#define CH 16
#define NH 12
#define PQ 4
#define PV 8

// workspace layout (float offsets)
#define OFF_Q     0          // 512*192
#define OFF_K     98304      // 512*192
#define OFF_V     196608     // 512*192
#define OFF_QRAW  294912     // 512*144
#define OFF_KVRAW 368640     // 512*432
#define OFF_QPTS  589824     // 512*144
#define OFF_KPTS  663552     // 512*144
#define OFF_VPTS  737280     // 512*288 AoS: [n][h*PV+p][xyz]
#define OFF_A     884736     // 512*12*512 = 3145728  (A0 logits, then probs in place)
#define OFF_CAT   4030464    // 512*2112
// end = 5111808 floats

// ---------------- kernel 1: fused projections, 16-row register tile ----------------
__global__ __launch_bounds__(256) void proj_kernel(
    const float* __restrict__ s,
    const float* __restrict__ Wq,  const float* __restrict__ bq,
    const float* __restrict__ Wkv, const float* __restrict__ bkv,
    const float* __restrict__ Wqp, const float* __restrict__ bqp,
    const float* __restrict__ Wkvp,const float* __restrict__ bkvp,
    float* __restrict__ ws)
{
    __shared__ float st[16 * CS];   // 24 KB
    const int n0 = blockIdx.x * 16;
    for (int idx = threadIdx.x * 4; idx < 16 * CS; idx += 256 * 4)
        *(float4*)&st[idx] = *(const float4*)&s[n0 * CS + idx];
    __syncthreads();

    const int tc = threadIdx.x & 31;
    const int tr = threadIdx.x >> 5;       // 0..7
    const int u0 = blockIdx.y * 128 + tc * 4;
    const int r0 = tr * 2;

    const float* W; const float* bptr; int ncol, lc0;
    if (u0 < 192)      { W = Wq;   bptr = bq;   ncol = 192; lc0 = u0; }
    else if (u0 < 576) { W = Wkv;  bptr = bkv;  ncol = 384; lc0 = u0 - 192; }
    else if (u0 < 720) { W = Wqp;  bptr = bqp;  ncol = 144; lc0 = u0 - 576; }
    else               { W = Wkvp; bptr = bkvp; ncol = 432; lc0 = u0 - 720; }

    float acc[2][4];
    #pragma unroll
    for (int r = 0; r < 2; r++)
        #pragma unroll
        for (int c = 0; c < 4; c++) acc[r][c] = 0.f;

    for (int k = 0; k < CS; k += 4) {
        float4 w0 = *(const float4*)&W[(k + 0) * ncol + lc0];
        float4 w1 = *(const float4*)&W[(k + 1) * ncol + lc0];
        float4 w2 = *(const float4*)&W[(k + 2) * ncol + lc0];
        float4 w3 = *(const float4*)&W[(k + 3) * ncol + lc0];
        #pragma unroll
        for (int r = 0; r < 2; r++) {
            float4 sv = *(const float4*)&st[(r0 + r) * CS + k];
            acc[r][0] += sv.x * w0.x + sv.y * w1.x + sv.z * w2.x + sv.w * w3.x;
            acc[r][1] += sv.x * w0.y + sv.y * w1.y + sv.z * w2.y + sv.w * w3.y;
            acc[r][2] += sv.x * w0.z + sv.y * w1.z + sv.z * w2.z + sv.w * w3.z;
            acc[r][3] += sv.x * w0.w + sv.y * w1.w + sv.z * w2.w + sv.w * w3.w;
        }
    }

    #pragma unroll
    for (int c = 0; c < 4; c++) {
        const int u = u0 + c;
        const float bias = bptr[lc0 + c];
        #pragma unroll
        for (int r = 0; r < 2; r++) {
            const int n = n0 + r0 + r;
            int oidx;
            if (u < 192) oidx = OFF_Q + n * 192 + u;
            else if (u < 576) {
                int lc = u - 192, h = lc >> 5, w = lc & 31;
                oidx = (w < 16) ? OFF_K + n * 192 + h * 16 + w
                                : OFF_V + n * 192 + h * 16 + (w - 16);
            } else if (u < 720) oidx = OFF_QRAW + n * 144 + (u - 576);
            else                oidx = OFF_KVRAW + n * 432 + (u - 720);
            ws[oidx] = acc[r][c] + bias;
        }
    }
}

// ---------------- kernel 2: rigid transform of point projections (AoS VPTS) ----------------
__global__ __launch_bounds__(192) void point_kernel(
    const float* __restrict__ t_trans, const float* __restrict__ t_rots,
    float* __restrict__ ws)
{
    const int n = blockIdx.x;
    const int t = threadIdx.x;
    __shared__ float R[9], tr[3];
    if (t < 9) R[t] = t_rots[n * 9 + t];
    if (t < 3) tr[t] = t_trans[n * 3 + t];
    __syncthreads();

    float x0, x1, x2;
    int base;
    if (t < 48) {
        int idx = t;
        x0 = ws[OFF_QRAW + n * 144 + 0 * 48 + idx];
        x1 = ws[OFF_QRAW + n * 144 + 1 * 48 + idx];
        x2 = ws[OFF_QRAW + n * 144 + 2 * 48 + idx];
        int h = idx >> 2, p = idx & 3;
        base = OFF_QPTS + ((n * NH + h) * PQ + p) * 3;
    } else {                       // t = 48..191 -> idx 0..143 (ALL kv points)
        int idx = t - 48;
        x0 = ws[OFF_KVRAW + n * 432 + 0 * 144 + idx];
        x1 = ws[OFF_KVRAW + n * 432 + 1 * 144 + idx];
        x2 = ws[OFF_KVRAW + n * 432 + 2 * 144 + idx];
        int h = idx / 12, p = idx % 12;
        if (p < PQ) base = OFF_KPTS + ((n * NH + h) * PQ + p) * 3;
        else        base = OFF_VPTS + (n * NH * PV + h * PV + (p - PQ)) * 3;
    }
    ws[base + 0] = R[0] * x0 + R[1] * x1 + R[2] * x2 + tr[0];
    ws[base + 1] = R[3] * x0 + R[4] * x1 + R[5] * x2 + tr[1];
    ws[base + 2] = R[6] * x0 + R[7] * x1 + R[8] * x2 + tr[2];
}

// ---------------- kernel 3: A0 = cqk*qk - 0.5*hw*d2 + mask ----------------
__global__ __launch_bounds__(192) void logitA_kernel(
    const float* __restrict__ mask, const float* __restrict__ hweights,
    float* __restrict__ ws)
{
    const int j0 = blockIdx.x * 16;
    const int i0 = blockIdx.y * 16;
    const int t = threadIdx.x;

    __shared__ float qt[16 * 200];
    __shared__ float kt[16 * 200];
    __shared__ float qpt[16 * 148];
    __shared__ float kpt[16 * 148];
    __shared__ float mi[16], mj[16];

    {
        const float* src = ws + OFF_Q + i0 * 192;
        for (int idx = t * 4; idx < 3072; idx += 768) {
            float4 v = *(const float4*)&src[idx];
            *(float4*)&qt[(idx / 192) * 200 + idx % 192] = v;
        }
    }
    {
        const float* src = ws + OFF_K + j0 * 192;
        for (int idx = t * 4; idx < 3072; idx += 768) {
            float4 v = *(const float4*)&src[idx];
            *(float4*)&kt[(idx / 192) * 200 + idx % 192] = v;
        }
    }
    {
        const float* src = ws + OFF_QPTS + i0 * 144;
        for (int idx = t * 4; idx < 2304; idx += 768) {
            float4 v = *(const float4*)&src[idx];
            *(float4*)&qpt[(idx / 144) * 148 + idx % 144] = v;
        }
    }
    {
        const float* src = ws + OFF_KPTS + j0 * 144;
        for (int idx = t * 4; idx < 2304; idx += 768) {
            float4 v = *(const float4*)&src[idx];
            *(float4*)&kpt[(idx / 144) * 148 + idx % 144] = v;
        }
    }
    if (t < 16) { mi[t] = mask[i0 + t]; mj[t] = mask[j0 + t]; }
    __syncthreads();

    const int jj = t & 15;
    const int h = t >> 4;
    const float hw = log1pf(expf(hweights[h])) * 0.13608276348795434f;
    const float cqk = 0.14433756729740643f;

    float4 kr0 = *(const float4*)&kt[jj * 200 + h * 16 + 0];
    float4 kr1 = *(const float4*)&kt[jj * 200 + h * 16 + 4];
    float4 kr2 = *(const float4*)&kt[jj * 200 + h * 16 + 8];
    float4 kr3 = *(const float4*)&kt[jj * 200 + h * 16 + 12];
    float4 kp0 = *(const float4*)&kpt[jj * 148 + h * 12 + 0];
    float4 kp1 = *(const float4*)&kpt[jj * 148 + h * 12 + 4];
    float4 kp2 = *(const float4*)&kpt[jj * 148 + h * 12 + 8];
    const float mjv = mj[jj];

    for (int ii = 0; ii < 16; ii++) {
        float4 q0 = *(const float4*)&qt[ii * 200 + h * 16 + 0];
        float4 q1 = *(const float4*)&qt[ii * 200 + h * 16 + 4];
        float4 q2 = *(const float4*)&qt[ii * 200 + h * 16 + 8];
        float4 q3 = *(const float4*)&qt[ii * 200 + h * 16 + 12];
        float qk = q0.x * kr0.x + q0.y * kr0.y + q0.z * kr0.z + q0.w * kr0.w
                 + q1.x * kr1.x + q1.y * kr1.y + q1.z * kr1.z + q1.w * kr1.w
                 + q2.x * kr2.x + q2.y * kr2.y + q2.z * kr2.z + q2.w * kr2.w
                 + q3.x * kr3.x + q3.y * kr3.y + q3.z * kr3.z + q3.w * kr3.w;
        float4 p0 = *(const float4*)&qpt[ii * 148 + h * 12 + 0];
        float4 p1 = *(const float4*)&qpt[ii * 148 + h * 12 + 4];
        float4 p2 = *(const float4*)&qpt[ii * 148 + h * 12 + 8];
        float e, d2 = 0.f;
        e = p0.x - kp0.x; d2 += e * e;  e = p0.y - kp0.y; d2 += e * e;
        e = p0.z - kp0.z; d2 += e * e;  e = p0.w - kp0.w; d2 += e * e;
        e = p1.x - kp1.x; d2 += e * e;  e = p1.y - kp1.y; d2 += e * e;
        e = p1.z - kp1.z; d2 += e * e;  e = p1.w - kp1.w; d2 += e * e;
        e = p2.x - kp2.x; d2 += e * e;  e = p2.y - kp2.y; d2 += e * e;
        e = p2.z - kp2.z; d2 += e * e;  e = p2.w - kp2.w; d2 += e * e;
        float sm = 100000.0f * (mi[ii] * mjv - 1.0f);
        ws[OFF_A + ((size_t)(i0 + ii) * NH + h) * N + j0 + jj] =
            qk * cqk - 0.5f * hw * d2 + sm;
    }
}

// ---------------- kernel 4: b = z@Wb fused with +A0 and softmax (one block per i) ----------------
// REVERTED to the wbt-LDS version (427-us era): 3 wbt b128 + 1 zt b128 per c-quad.
__global__ __launch_bounds__(512) void bsoft_kernel(
    const float* __restrict__ z, const float* __restrict__ Wb,
    const float* __restrict__ bb, float* __restrict__ ws)
{
    const int i = blockIdx.x;
    const int t = threadIdx.x;
    __shared__ float zt[128 * 132];   // 67.6 KB, stride 132 -> conflict-free b128 rows
    __shared__ float wbt[12 * 132];   // Wb transposed [h][c]
    __shared__ float wred[8][4];      // per-wave softmax partials

    for (int idx = t; idx < CZ * NH; idx += 512) {
        int c = idx / NH, h = idx % NH;
        wbt[h * 132 + c] = Wb[idx];
    }

    const int jj = t & 127;
    const int hg = t >> 7;      // 0..3
    const int h0 = hg * 3;
    const float bb0 = bb[h0], bb1 = bb[h0 + 1], bb2 = bb[h0 + 2];
    const float cb = 0.5773502691896258f;

    float lg[3][4];

    for (int T = 0; T < 4; T++) {
        __syncthreads();
        const float* zsrc = z + ((size_t)i * N + T * 128) * CZ;
        for (int idx = t * 4; idx < 16384; idx += 2048) {
            float4 v = *(const float4*)&zsrc[idx];
            *(float4*)&zt[(idx >> 7) * 132 + (idx & 127)] = v;
        }
        __syncthreads();

        float a0 = bb0, a1 = bb1, a2 = bb2;
        const float* zr = &zt[jj * 132];
        const float* w0 = &wbt[(h0 + 0) * 132];
        const float* w1 = &wbt[(h0 + 1) * 132];
        const float* w2 = &wbt[(h0 + 2) * 132];
        #pragma unroll
        for (int c = 0; c < CZ; c += 4) {
            float4 zq = *(const float4*)&zr[c];
            float4 q0 = *(const float4*)&w0[c];
            float4 q1 = *(const float4*)&w1[c];
            float4 q2 = *(const float4*)&w2[c];
            a0 += zq.x * q0.x + zq.y * q0.y + zq.z * q0.z + zq.w * q0.w;
            a1 += zq.x * q1.x + zq.y * q1.y + zq.z * q1.z + zq.w * q1.w;
            a2 += zq.x * q2.x + zq.y * q2.y + zq.z * q2.z + zq.w * q2.w;
        }
        const float* arow = ws + OFF_A + (size_t)i * NH * N + T * 128 + jj;
        lg[0][T] = arow[(size_t)(h0 + 0) * N] + cb * a0;
        lg[1][T] = arow[(size_t)(h0 + 1) * N] + cb * a1;
        lg[2][T] = arow[(size_t)(h0 + 2) * N] + cb * a2;
    }

    const int wv = t >> 6;
    float mx[3], sm[3];
    #pragma unroll
    for (int r = 0; r < 3; r++) {
        float m = fmaxf(fmaxf(lg[r][0], lg[r][1]), fmaxf(lg[r][2], lg[r][3]));
        #pragma unroll
        for (int o = 32; o > 0; o >>= 1) m = fmaxf(m, __shfl_xor(m, o));
        mx[r] = m;
    }
    if ((t & 63) == 0) {
        wred[wv][0] = mx[0]; wred[wv][1] = mx[1]; wred[wv][2] = mx[2];
    }
    __syncthreads();
    #pragma unroll
    for (int r = 0; r < 3; r++)
        mx[r] = fmaxf(wred[hg * 2][r], wred[hg * 2 + 1][r]);
    __syncthreads();   // protect wred reuse
    #pragma unroll
    for (int r = 0; r < 3; r++) {
        float s = 0.f;
        #pragma unroll
        for (int T = 0; T < 4; T++) { lg[r][T] = __expf(lg[r][T] - mx[r]); s += lg[r][T]; }
        #pragma unroll
        for (int o = 32; o > 0; o >>= 1) s += __shfl_xor(s, o);
        sm[r] = s;
    }
    if ((t & 63) == 0) {
        wred[wv][0] = sm[0]; wred[wv][1] = sm[1]; wred[wv][2] = sm[2];
    }
    __syncthreads();
    #pragma unroll
    for (int r = 0; r < 3; r++) {
        float inv = 1.0f / (wred[hg * 2][r] + wred[hg * 2 + 1][r]);
        float* prow = ws + OFF_A + ((size_t)i * NH + h0 + r) * N + jj;
        #pragma unroll
        for (int T = 0; T < 4; T++)
            prow[T * 128] = lg[r][T] * inv;
    }
}

// ---------------- kernel 5: o / o_pt / o_pair — 2-way j-split, 960 threads ----------------
// Roles x 2 j-halves: [0,384) o_pair, [384,768) o, [768,960) o_pt.
// Each half accumulates over 256 j; half-1 partials go through LDS; half-0 finishes.
__global__ __launch_bounds__(960) void finish_kernel(
    const float* __restrict__ z, const float* __restrict__ t_trans,
    const float* __restrict__ t_rots, const float* __restrict__ ws_c,
    float* __restrict__ ws)
{
    const int i = blockIdx.x;
    const int t = threadIdx.x;
    __shared__ float a_s[12 * 520];        // 24.96 KB
    __shared__ float pr_pair[192 * 8];     // 6 KB partials
    __shared__ float pr_o[192];
    __shared__ float pr_pt[96 * 3];

    {
        const float* src = ws_c + OFF_A + (size_t)i * (NH * N);
        for (int idx = t * 4; idx < NH * N; idx += 960 * 4) {
            float4 v = *(const float4*)&src[idx];
            int h = idx >> 9, j = idx & 511;
            *(float4*)&a_s[h * 520 + j] = v;
        }
    }
    __syncthreads();

    float* cat = ws + OFF_CAT + (size_t)i * 2112;

    float4 accA = {0,0,0,0}, accB = {0,0,0,0};   // o_pair
    float accO = 0.f;                            // o
    float g0 = 0.f, g1 = 0.f, g2 = 0.f;          // o_pt

    int jh = 0, v = 0;

    if (t < 384) {          // o_pair
        jh = (t >= 192); v = t - jh * 192;
        const int cg = v & 31;
        const int hs = v >> 5;
        const float* zb = z + (size_t)i * N * CZ + cg * 4;
        const float* ahA = a_s + hs * 520;
        const float* ahB = a_s + (hs + 6) * 520;
        const int j0 = jh * 256;
        #pragma unroll 4
        for (int jo = 0; jo < 256; jo += 4) {
            const int j = j0 + jo;
            float4 aA = *(const float4*)&ahA[j];
            float4 aB = *(const float4*)&ahB[j];
            float4 z0 = *(const float4*)&zb[(size_t)(j + 0) * CZ];
            float4 z1 = *(const float4*)&zb[(size_t)(j + 1) * CZ];
            float4 z2 = *(const float4*)&zb[(size_t)(j + 2) * CZ];
            float4 z3 = *(const float4*)&zb[(size_t)(j + 3) * CZ];
            accA.x += aA.x * z0.x + aA.y * z1.x + aA.z * z2.x + aA.w * z3.x;
            accA.y += aA.x * z0.y + aA.y * z1.y + aA.z * z2.y + aA.w * z3.y;
            accA.z += aA.x * z0.z + aA.y * z1.z + aA.z * z2.z + aA.w * z3.z;
            accA.w += aA.x * z0.w + aA.y * z1.w + aA.z * z2.w + aA.w * z3.w;
            accB.x += aB.x * z0.x + aB.y * z1.x + aB.z * z2.x + aB.w * z3.x;
            accB.y += aB.x * z0.y + aB.y * z1.y + aB.z * z2.y + aB.w * z3.y;
            accB.z += aB.x * z0.z + aB.y * z1.z + aB.z * z2.z + aB.w * z3.z;
            accB.w += aB.x * z0.w + aB.y * z1.w + aB.z * z2.w + aB.w * z3.w;
        }
    } else if (t < 768) {   // o
        const int u = t - 384;
        jh = (u >= 192); v = u - jh * 192;
        const int h = v >> 4, cc = v & 15;
        const float* vcol = ws_c + OFF_V + h * 16 + cc;
        const float* ah = a_s + h * 520;
        const int j0 = jh * 256;
        #pragma unroll 8
        for (int jo = 0; jo < 256; jo++) {
            const int j = j0 + jo;
            accO += ah[j] * vcol[j * 192];
        }
    } else {                // o_pt (AoS)
        const int u = t - 768;
        jh = (u >= 96); v = u - jh * 96;
        const int h = v >> 3, p = v & 7;
        const float* vp = ws_c + OFF_VPTS + (h * PV + p) * 3;
        const float* ah = a_s + h * 520;
        const int j0 = jh * 256;
        #pragma unroll 4
        for (int jo = 0; jo < 256; jo++) {
            const int j = j0 + jo;
            float av = ah[j];
            const float* vpj = vp + (size_t)j * (NH * PV * 3);
            g0 += av * vpj[0]; g1 += av * vpj[1]; g2 += av * vpj[2];
        }
    }

    // half-1 publishes partials
    if (jh == 1) {
        if (t < 384) {
            float* d = pr_pair + v * 8;
            d[0] = accA.x; d[1] = accA.y; d[2] = accA.z; d[3] = accA.w;
            d[4] = accB.x; d[5] = accB.y; d[6] = accB.z; d[7] = accB.w;
        } else if (t < 768) {
            pr_o[v] = accO;
        } else {
            pr_pt[v * 3 + 0] = g0; pr_pt[v * 3 + 1] = g1; pr_pt[v * 3 + 2] = g2;
        }
    }
    __syncthreads();

    // half-0 combines + epilogue
    if (jh == 0) {
        if (t < 384) {
            const float* d = pr_pair + v * 8;
            accA.x += d[0]; accA.y += d[1]; accA.z += d[2]; accA.w += d[3];
            accB.x += d[4]; accB.y += d[5]; accB.z += d[6]; accB.w += d[7];
            const int cg = v & 31, hs = v >> 5;
            *(float4*)&cat[576 + hs * CZ + cg * 4]       = accA;
            *(float4*)&cat[576 + (hs + 6) * CZ + cg * 4] = accB;
        } else if (t < 768) {
            accO += pr_o[v];
            const int h = v >> 4, cc = v & 15;
            cat[h * 16 + cc] = accO;
        } else {
            g0 += pr_pt[v * 3 + 0]; g1 += pr_pt[v * 3 + 1]; g2 += pr_pt[v * 3 + 2];
            float R[9], ti[3];
            #pragma unroll
            for (int x = 0; x < 9; x++) R[x] = t_rots[i * 9 + x];
            #pragma unroll
            for (int x = 0; x < 3; x++) ti[x] = t_trans[i * 3 + x];
            g0 -= ti[0]; g1 -= ti[1]; g2 -= ti[2];
            float l0 = R[0] * g0 + R[3] * g1 + R[6] * g2;
            float l1 = R[1] * g0 + R[4] * g1 + R[7] * g2;
            float l2 = R[2] * g0 + R[5] * g1 + R[8] * g2;
            float nrm = sqrtf(l0 * l0 + l1 * l1 + l2 * l2 + 1e-8f);
            const int h = v >> 3, p = v & 7;
            int e = h * PV + p;
            cat[192 + e] = l0;
            cat[288 + e] = l1;
            cat[384 + e] = l2;
            cat[480 + e] = nrm;
        }
    }
}

// ---------------- kernel 6a: init out with bias ----------------
__global__ __launch_bounds__(384) void init_out_kernel(
    const float* __restrict__ bout, float* __restrict__ out)
{
    out[(size_t)blockIdx.x * 384 + threadIdx.x] = bout[threadIdx.x];
}

// ---------------- kernel 6b: out += cat @ Wout (k-split, atomic) ----------------
__global__ __launch_bounds__(384) void out_kernel(
    const float* __restrict__ Wout, const float* __restrict__ ws,
    float* __restrict__ out)
{
    const int rt = blockIdx.x;
    const int kc = blockIdx.y;
    const int t = threadIdx.x;
    __shared__ float ct[16 * 264];
    for (int idx = t * 4; idx < 16 * 264; idx += 384 * 4) {
        int rr = idx / 264, kk = idx % 264;
        *(float4*)&ct[idx] =
            *(const float4*)&ws[OFF_CAT + (size_t)(rt * 16 + rr) * 2112 + kc * 264 + kk];
    }
    __syncthreads();
    const int cq = t % 96, rg = t / 96;
    const int c0 = cq * 4;
    float acc[4][4] = {};
    const float* Wp = Wout + (size_t)kc * 264 * 384 + c0;
    for (int kk = 0; kk < 264; kk += 4) {
        float4 w0 = *(const float4*)&Wp[(size_t)(kk + 0) * 384];
        float4 w1 = *(const float4*)&Wp[(size_t)(kk + 1) * 384];
        float4 w2 = *(const float4*)&Wp[(size_t)(kk + 2) * 384];
        float4 w3 = *(const float4*)&Wp[(size_t)(kk + 3) * 384];
        #pragma unroll
        for (int r = 0; r < 4; r++) {
            float4 sv = *(const float4*)&ct[(rg * 4 + r) * 264 + kk];
            acc[r][0] += sv.x * w0.x + sv.y * w1.x + sv.z * w2.x + sv.w * w3.x;
            acc[r][1] += sv.x * w0.y + sv.y * w1.y + sv.z * w2.y + sv.w * w3.y;
            acc[r][2] += sv.x * w0.z + sv.y * w1.z + sv.z * w2.z + sv.w * w3.z;
            acc[r][3] += sv.x * w0.w + sv.y * w1.w + sv.z * w2.w + sv.w * w3.w;
        }
    }
    #pragma unroll
    for (int r = 0; r < 4; r++) {
        float* op = out + (size_t)(rt * 16 + rg * 4 + r) * 384 + c0;
        atomicAdd(&op[0], acc[r][0]);
        atomicAdd(&op[1], acc[r][1]);
        atomicAdd(&op[2], acc[r][2]);
        atomicAdd(&op[3], acc[r][3]);
    }
}

extern "C" void kernel_launch(void* const* d_in, const int* in_sizes, int n_in,
                              void* d_out, int out_size, void* d_ws, size_t ws_size,
                              hipStream_t stream) {
    const float* s       = (const float*)d_in[0];
    const float* z       = (const float*)d_in[1];
    const float* t_trans = (const float*)d_in[2];
    const float* t_rots  = (const float*)d_in[3];
    const float* mask    = (const float*)d_in[4];
    const float* Wq      = (const float*)d_in[5];
    const float* bq      = (const float*)d_in[6];
    const float* Wkv     = (const float*)d_in[7];
    const float* bkv     = (const float*)d_in[8];
    const float* Wqp     = (const float*)d_in[9];
    const float* bqp     = (const float*)d_in[10];
    const float* Wkvp    = (const float*)d_in[11];
    const float* bkvp    = (const float*)d_in[12];
    const float* Wb      = (const float*)d_in[13];
    const float* bb      = (const float*)d_in[14];
    const float* hweights= (const float*)d_in[15];
    const float* Wout    = (const float*)d_in[16];
    const float* bout    = (const float*)d_in[17];
    float* ws  = (float*)d_ws;
    float* out = (float*)d_out;

    init_out_kernel<<<512, 384, 0, stream>>>(bout, out);
    proj_kernel<<<dim3(32, 9), 256, 0, stream>>>(s, Wq, bq, Wkv, bkv, Wqp, bqp, Wkvp, bkvp, ws);
    point_kernel<<<512, 192, 0, stream>>>(t_trans, t_rots, ws);
    logitA_kernel<<<dim3(32, 32), 192, 0, stream>>>(mask, hweights, ws);
    bsoft_kernel<<<512, 512, 0, stream>>>(z, Wb, bb, ws);
    finish_kernel<<<512, 960, 0, stream>>>(z, t_trans, t_rots, ws, ws);
    out_kernel<<<dim3(32, 8), 384, 0, stream>>>(Wout, ws, out);
}

// Round 6
// 395.899 us; speedup vs baseline: 1.3991x; 1.1206x over previous
//
#include <hip/hip_runtime.h>
#include <math.h>

#define N 512
#define CS 384
#define CZ 128
#define CH 16
#define NH 12
#define PQ 4
#define PV 8

// workspace layout (float offsets)
#define OFF_Q     0          // 512*192
#define OFF_K     98304      // 512*192
#define OFF_V     196608     // 512*192
#define OFF_QRAW  294912     // 512*144
#define OFF_KVRAW 368640     // 512*432
#define OFF_QPTS  589824     // 512*144
#define OFF_KPTS  663552     // 512*144
#define OFF_VPTS  737280     // 512*288 AoS: [n][h*PV+p][xyz]
#define OFF_A     884736     // 512*12*512 = 3145728  (A0 logits -> probs -> out partials)
#define OFF_CAT   4030464    // 512*2112
// end = 5111808 floats
// NOTE: after finish_kernel, OFF_A is dead; out_kernel reuses it for
// k-split partials [16][512][384] = 3145728 floats (exact fit).

// ---------------- kernel 1: fused projections, 16-row register tile ----------------
__global__ __launch_bounds__(256) void proj_kernel(
    const float* __restrict__ s,
    const float* __restrict__ Wq,  const float* __restrict__ bq,
    const float* __restrict__ Wkv, const float* __restrict__ bkv,
    const float* __restrict__ Wqp, const float* __restrict__ bqp,
    const float* __restrict__ Wkvp,const float* __restrict__ bkvp,
    float* __restrict__ ws)
{
    __shared__ float st[16 * CS];   // 24 KB
    const int n0 = blockIdx.x * 16;
    for (int idx = threadIdx.x * 4; idx < 16 * CS; idx += 256 * 4)
        *(float4*)&st[idx] = *(const float4*)&s[n0 * CS + idx];
    __syncthreads();

    const int tc = threadIdx.x & 31;
    const int tr = threadIdx.x >> 5;       // 0..7
    const int u0 = blockIdx.y * 128 + tc * 4;
    const int r0 = tr * 2;

    const float* W; const float* bptr; int ncol, lc0;
    if (u0 < 192)      { W = Wq;   bptr = bq;   ncol = 192; lc0 = u0; }
    else if (u0 < 576) { W = Wkv;  bptr = bkv;  ncol = 384; lc0 = u0 - 192; }
    else if (u0 < 720) { W = Wqp;  bptr = bqp;  ncol = 144; lc0 = u0 - 576; }
    else               { W = Wkvp; bptr = bkvp; ncol = 432; lc0 = u0 - 720; }

    float acc[2][4];
    #pragma unroll
    for (int r = 0; r < 2; r++)
        #pragma unroll
        for (int c = 0; c < 4; c++) acc[r][c] = 0.f;

    for (int k = 0; k < CS; k += 4) {
        float4 w0 = *(const float4*)&W[(k + 0) * ncol + lc0];
        float4 w1 = *(const float4*)&W[(k + 1) * ncol + lc0];
        float4 w2 = *(const float4*)&W[(k + 2) * ncol + lc0];
        float4 w3 = *(const float4*)&W[(k + 3) * ncol + lc0];
        #pragma unroll
        for (int r = 0; r < 2; r++) {
            float4 sv = *(const float4*)&st[(r0 + r) * CS + k];
            acc[r][0] += sv.x * w0.x + sv.y * w1.x + sv.z * w2.x + sv.w * w3.x;
            acc[r][1] += sv.x * w0.y + sv.y * w1.y + sv.z * w2.y + sv.w * w3.y;
            acc[r][2] += sv.x * w0.z + sv.y * w1.z + sv.z * w2.z + sv.w * w3.z;
            acc[r][3] += sv.x * w0.w + sv.y * w1.w + sv.z * w2.w + sv.w * w3.w;
        }
    }

    #pragma unroll
    for (int c = 0; c < 4; c++) {
        const int u = u0 + c;
        const float bias = bptr[lc0 + c];
        #pragma unroll
        for (int r = 0; r < 2; r++) {
            const int n = n0 + r0 + r;
            int oidx;
            if (u < 192) oidx = OFF_Q + n * 192 + u;
            else if (u < 576) {
                int lc = u - 192, h = lc >> 5, w = lc & 31;
                oidx = (w < 16) ? OFF_K + n * 192 + h * 16 + w
                                : OFF_V + n * 192 + h * 16 + (w - 16);
            } else if (u < 720) oidx = OFF_QRAW + n * 144 + (u - 576);
            else                oidx = OFF_KVRAW + n * 432 + (u - 720);
            ws[oidx] = acc[r][c] + bias;
        }
    }
}

// ---------------- kernel 2: rigid transform of point projections (AoS VPTS) ----------------
__global__ __launch_bounds__(192) void point_kernel(
    const float* __restrict__ t_trans, const float* __restrict__ t_rots,
    float* __restrict__ ws)
{
    const int n = blockIdx.x;
    const int t = threadIdx.x;
    __shared__ float R[9], tr[3];
    if (t < 9) R[t] = t_rots[n * 9 + t];
    if (t < 3) tr[t] = t_trans[n * 3 + t];
    __syncthreads();

    float x0, x1, x2;
    int base;
    if (t < 48) {
        int idx = t;
        x0 = ws[OFF_QRAW + n * 144 + 0 * 48 + idx];
        x1 = ws[OFF_QRAW + n * 144 + 1 * 48 + idx];
        x2 = ws[OFF_QRAW + n * 144 + 2 * 48 + idx];
        int h = idx >> 2, p = idx & 3;
        base = OFF_QPTS + ((n * NH + h) * PQ + p) * 3;
    } else {                       // t = 48..191 -> idx 0..143 (ALL kv points)
        int idx = t - 48;
        x0 = ws[OFF_KVRAW + n * 432 + 0 * 144 + idx];
        x1 = ws[OFF_KVRAW + n * 432 + 1 * 144 + idx];
        x2 = ws[OFF_KVRAW + n * 432 + 2 * 144 + idx];
        int h = idx / 12, p = idx % 12;
        if (p < PQ) base = OFF_KPTS + ((n * NH + h) * PQ + p) * 3;
        else        base = OFF_VPTS + (n * NH * PV + h * PV + (p - PQ)) * 3;
    }
    ws[base + 0] = R[0] * x0 + R[1] * x1 + R[2] * x2 + tr[0];
    ws[base + 1] = R[3] * x0 + R[4] * x1 + R[5] * x2 + tr[1];
    ws[base + 2] = R[6] * x0 + R[7] * x1 + R[8] * x2 + tr[2];
}

// ---------------- kernel 3: A0 = cqk*qk - 0.5*hw*d2 + mask ----------------
__global__ __launch_bounds__(192) void logitA_kernel(
    const float* __restrict__ mask, const float* __restrict__ hweights,
    float* __restrict__ ws)
{
    const int j0 = blockIdx.x * 16;
    const int i0 = blockIdx.y * 16;
    const int t = threadIdx.x;

    __shared__ float qt[16 * 200];
    __shared__ float kt[16 * 200];
    __shared__ float qpt[16 * 148];
    __shared__ float kpt[16 * 148];
    __shared__ float mi[16], mj[16];

    {
        const float* src = ws + OFF_Q + i0 * 192;
        for (int idx = t * 4; idx < 3072; idx += 768) {
            float4 v = *(const float4*)&src[idx];
            *(float4*)&qt[(idx / 192) * 200 + idx % 192] = v;
        }
    }
    {
        const float* src = ws + OFF_K + j0 * 192;
        for (int idx = t * 4; idx < 3072; idx += 768) {
            float4 v = *(const float4*)&src[idx];
            *(float4*)&kt[(idx / 192) * 200 + idx % 192] = v;
        }
    }
    {
        const float* src = ws + OFF_QPTS + i0 * 144;
        for (int idx = t * 4; idx < 2304; idx += 768) {
            float4 v = *(const float4*)&src[idx];
            *(float4*)&qpt[(idx / 144) * 148 + idx % 144] = v;
        }
    }
    {
        const float* src = ws + OFF_KPTS + j0 * 144;
        for (int idx = t * 4; idx < 2304; idx += 768) {
            float4 v = *(const float4*)&src[idx];
            *(float4*)&kpt[(idx / 144) * 148 + idx % 144] = v;
        }
    }
    if (t < 16) { mi[t] = mask[i0 + t]; mj[t] = mask[j0 + t]; }
    __syncthreads();

    const int jj = t & 15;
    const int h = t >> 4;
    const float hw = log1pf(expf(hweights[h])) * 0.13608276348795434f;
    const float cqk = 0.14433756729740643f;

    float4 kr0 = *(const float4*)&kt[jj * 200 + h * 16 + 0];
    float4 kr1 = *(const float4*)&kt[jj * 200 + h * 16 + 4];
    float4 kr2 = *(const float4*)&kt[jj * 200 + h * 16 + 8];
    float4 kr3 = *(const float4*)&kt[jj * 200 + h * 16 + 12];
    float4 kp0 = *(const float4*)&kpt[jj * 148 + h * 12 + 0];
    float4 kp1 = *(const float4*)&kpt[jj * 148 + h * 12 + 4];
    float4 kp2 = *(const float4*)&kpt[jj * 148 + h * 12 + 8];
    const float mjv = mj[jj];

    for (int ii = 0; ii < 16; ii++) {
        float4 q0 = *(const float4*)&qt[ii * 200 + h * 16 + 0];
        float4 q1 = *(const float4*)&qt[ii * 200 + h * 16 + 4];
        float4 q2 = *(const float4*)&qt[ii * 200 + h * 16 + 8];
        float4 q3 = *(const float4*)&qt[ii * 200 + h * 16 + 12];
        float qk = q0.x * kr0.x + q0.y * kr0.y + q0.z * kr0.z + q0.w * kr0.w
                 + q1.x * kr1.x + q1.y * kr1.y + q1.z * kr1.z + q1.w * kr1.w
                 + q2.x * kr2.x + q2.y * kr2.y + q2.z * kr2.z + q2.w * kr2.w
                 + q3.x * kr3.x + q3.y * kr3.y + q3.z * kr3.z + q3.w * kr3.w;
        float4 p0 = *(const float4*)&qpt[ii * 148 + h * 12 + 0];
        float4 p1 = *(const float4*)&qpt[ii * 148 + h * 12 + 4];
        float4 p2 = *(const float4*)&qpt[ii * 148 + h * 12 + 8];
        float e, d2 = 0.f;
        e = p0.x - kp0.x; d2 += e * e;  e = p0.y - kp0.y; d2 += e * e;
        e = p0.z - kp0.z; d2 += e * e;  e = p0.w - kp0.w; d2 += e * e;
        e = p1.x - kp1.x; d2 += e * e;  e = p1.y - kp1.y; d2 += e * e;
        e = p1.z - kp1.z; d2 += e * e;  e = p1.w - kp1.w; d2 += e * e;
        e = p2.x - kp2.x; d2 += e * e;  e = p2.y - kp2.y; d2 += e * e;
        e = p2.z - kp2.z; d2 += e * e;  e = p2.w - kp2.w; d2 += e * e;
        float sm = 100000.0f * (mi[ii] * mjv - 1.0f);
        ws[OFF_A + ((size_t)(i0 + ii) * NH + h) * N + j0 + jj] =
            qk * cqk - 0.5f * hw * d2 + sm;
    }
}

// ---------------- kernel 4: b = z@Wb fused with +A0 and softmax (one block per i) ----------------
__global__ __launch_bounds__(512) void bsoft_kernel(
    const float* __restrict__ z, const float* __restrict__ Wb,
    const float* __restrict__ bb, float* __restrict__ ws)
{
    const int i = blockIdx.x;
    const int t = threadIdx.x;
    __shared__ float zt[128 * 132];   // 67.6 KB, stride 132 -> conflict-free b128 rows
    __shared__ float wbt[12 * 132];   // Wb transposed [h][c]
    __shared__ float wred[8][4];      // per-wave softmax partials

    for (int idx = t; idx < CZ * NH; idx += 512) {
        int c = idx / NH, h = idx % NH;
        wbt[h * 132 + c] = Wb[idx];
    }

    const int jj = t & 127;
    const int hg = t >> 7;      // 0..3
    const int h0 = hg * 3;
    const float bb0 = bb[h0], bb1 = bb[h0 + 1], bb2 = bb[h0 + 2];
    const float cb = 0.5773502691896258f;

    float lg[3][4];

    for (int T = 0; T < 4; T++) {
        __syncthreads();
        const float* zsrc = z + ((size_t)i * N + T * 128) * CZ;
        for (int idx = t * 4; idx < 16384; idx += 2048) {
            float4 v = *(const float4*)&zsrc[idx];
            *(float4*)&zt[(idx >> 7) * 132 + (idx & 127)] = v;
        }
        __syncthreads();

        float a0 = bb0, a1 = bb1, a2 = bb2;
        const float* zr = &zt[jj * 132];
        const float* w0 = &wbt[(h0 + 0) * 132];
        const float* w1 = &wbt[(h0 + 1) * 132];
        const float* w2 = &wbt[(h0 + 2) * 132];
        #pragma unroll
        for (int c = 0; c < CZ; c += 4) {
            float4 zq = *(const float4*)&zr[c];
            float4 q0 = *(const float4*)&w0[c];
            float4 q1 = *(const float4*)&w1[c];
            float4 q2 = *(const float4*)&w2[c];
            a0 += zq.x * q0.x + zq.y * q0.y + zq.z * q0.z + zq.w * q0.w;
            a1 += zq.x * q1.x + zq.y * q1.y + zq.z * q1.z + zq.w * q1.w;
            a2 += zq.x * q2.x + zq.y * q2.y + zq.z * q2.z + zq.w * q2.w;
        }
        const float* arow = ws + OFF_A + (size_t)i * NH * N + T * 128 + jj;
        lg[0][T] = arow[(size_t)(h0 + 0) * N] + cb * a0;
        lg[1][T] = arow[(size_t)(h0 + 1) * N] + cb * a1;
        lg[2][T] = arow[(size_t)(h0 + 2) * N] + cb * a2;
    }

    const int wv = t >> 6;
    float mx[3], sm[3];
    #pragma unroll
    for (int r = 0; r < 3; r++) {
        float m = fmaxf(fmaxf(lg[r][0], lg[r][1]), fmaxf(lg[r][2], lg[r][3]));
        #pragma unroll
        for (int o = 32; o > 0; o >>= 1) m = fmaxf(m, __shfl_xor(m, o));
        mx[r] = m;
    }
    if ((t & 63) == 0) {
        wred[wv][0] = mx[0]; wred[wv][1] = mx[1]; wred[wv][2] = mx[2];
    }
    __syncthreads();
    #pragma unroll
    for (int r = 0; r < 3; r++)
        mx[r] = fmaxf(wred[hg * 2][r], wred[hg * 2 + 1][r]);
    __syncthreads();   // protect wred reuse
    #pragma unroll
    for (int r = 0; r < 3; r++) {
        float s = 0.f;
        #pragma unroll
        for (int T = 0; T < 4; T++) { lg[r][T] = __expf(lg[r][T] - mx[r]); s += lg[r][T]; }
        #pragma unroll
        for (int o = 32; o > 0; o >>= 1) s += __shfl_xor(s, o);
        sm[r] = s;
    }
    if ((t & 63) == 0) {
        wred[wv][0] = sm[0]; wred[wv][1] = sm[1]; wred[wv][2] = sm[2];
    }
    __syncthreads();
    #pragma unroll
    for (int r = 0; r < 3; r++) {
        float inv = 1.0f / (wred[hg * 2][r] + wred[hg * 2 + 1][r]);
        float* prow = ws + OFF_A + ((size_t)i * NH + h0 + r) * N + jj;
        #pragma unroll
        for (int T = 0; T < 4; T++)
            prow[T * 128] = lg[r][T] * inv;
    }
}

// ---------------- kernel 5: o / o_pt / o_pair — 2-way j-split, 960 threads ----------------
__global__ __launch_bounds__(960) void finish_kernel(
    const float* __restrict__ z, const float* __restrict__ t_trans,
    const float* __restrict__ t_rots, const float* __restrict__ ws_c,
    float* __restrict__ ws)
{
    const int i = blockIdx.x;
    const int t = threadIdx.x;
    __shared__ float a_s[12 * 520];        // 24.96 KB
    __shared__ float pr_pair[192 * 8];     // 6 KB partials
    __shared__ float pr_o[192];
    __shared__ float pr_pt[96 * 3];

    {
        const float* src = ws_c + OFF_A + (size_t)i * (NH * N);
        for (int idx = t * 4; idx < NH * N; idx += 960 * 4) {
            float4 v = *(const float4*)&src[idx];
            int h = idx >> 9, j = idx & 511;
            *(float4*)&a_s[h * 520 + j] = v;
        }
    }
    __syncthreads();

    float* cat = ws + OFF_CAT + (size_t)i * 2112;

    float4 accA = {0,0,0,0}, accB = {0,0,0,0};   // o_pair
    float accO = 0.f;                            // o
    float g0 = 0.f, g1 = 0.f, g2 = 0.f;          // o_pt

    int jh = 0, v = 0;

    if (t < 384) {          // o_pair
        jh = (t >= 192); v = t - jh * 192;
        const int cg = v & 31;
        const int hs = v >> 5;
        const float* zb = z + (size_t)i * N * CZ + cg * 4;
        const float* ahA = a_s + hs * 520;
        const float* ahB = a_s + (hs + 6) * 520;
        const int j0 = jh * 256;
        #pragma unroll 4
        for (int jo = 0; jo < 256; jo += 4) {
            const int j = j0 + jo;
            float4 aA = *(const float4*)&ahA[j];
            float4 aB = *(const float4*)&ahB[j];
            float4 z0 = *(const float4*)&zb[(size_t)(j + 0) * CZ];
            float4 z1 = *(const float4*)&zb[(size_t)(j + 1) * CZ];
            float4 z2 = *(const float4*)&zb[(size_t)(j + 2) * CZ];
            float4 z3 = *(const float4*)&zb[(size_t)(j + 3) * CZ];
            accA.x += aA.x * z0.x + aA.y * z1.x + aA.z * z2.x + aA.w * z3.x;
            accA.y += aA.x * z0.y + aA.y * z1.y + aA.z * z2.y + aA.w * z3.y;
            accA.z += aA.x * z0.z + aA.y * z1.z + aA.z * z2.z + aA.w * z3.z;
            accA.w += aA.x * z0.w + aA.y * z1.w + aA.z * z2.w + aA.w * z3.w;
            accB.x += aB.x * z0.x + aB.y * z1.x + aB.z * z2.x + aB.w * z3.x;
            accB.y += aB.x * z0.y + aB.y * z1.y + aB.z * z2.y + aB.w * z3.y;
            accB.z += aB.x * z0.z + aB.y * z1.z + aB.z * z2.z + aB.w * z3.z;
            accB.w += aB.x * z0.w + aB.y * z1.w + aB.z * z2.w + aB.w * z3.w;
        }
    } else if (t < 768) {   // o
        const int u = t - 384;
        jh = (u >= 192); v = u - jh * 192;
        const int h = v >> 4, cc = v & 15;
        const float* vcol = ws_c + OFF_V + h * 16 + cc;
        const float* ah = a_s + h * 520;
        const int j0 = jh * 256;
        #pragma unroll 8
        for (int jo = 0; jo < 256; jo++) {
            const int j = j0 + jo;
            accO += ah[j] * vcol[j * 192];
        }
    } else {                // o_pt (AoS)
        const int u = t - 768;
        jh = (u >= 96); v = u - jh * 96;
        const int h = v >> 3, p = v & 7;
        const float* vp = ws_c + OFF_VPTS + (h * PV + p) * 3;
        const float* ah = a_s + h * 520;
        const int j0 = jh * 256;
        #pragma unroll 4
        for (int jo = 0; jo < 256; jo++) {
            const int j = j0 + jo;
            float av = ah[j];
            const float* vpj = vp + (size_t)j * (NH * PV * 3);
            g0 += av * vpj[0]; g1 += av * vpj[1]; g2 += av * vpj[2];
        }
    }

    // half-1 publishes partials
    if (jh == 1) {
        if (t < 384) {
            float* d = pr_pair + v * 8;
            d[0] = accA.x; d[1] = accA.y; d[2] = accA.z; d[3] = accA.w;
            d[4] = accB.x; d[5] = accB.y; d[6] = accB.z; d[7] = accB.w;
        } else if (t < 768) {
            pr_o[v] = accO;
        } else {
            pr_pt[v * 3 + 0] = g0; pr_pt[v * 3 + 1] = g1; pr_pt[v * 3 + 2] = g2;
        }
    }
    __syncthreads();

    // half-0 combines + epilogue
    if (jh == 0) {
        if (t < 384) {
            const float* d = pr_pair + v * 8;
            accA.x += d[0]; accA.y += d[1]; accA.z += d[2]; accA.w += d[3];
            accB.x += d[4]; accB.y += d[5]; accB.z += d[6]; accB.w += d[7];
            const int cg = v & 31, hs = v >> 5;
            *(float4*)&cat[576 + hs * CZ + cg * 4]       = accA;
            *(float4*)&cat[576 + (hs + 6) * CZ + cg * 4] = accB;
        } else if (t < 768) {
            accO += pr_o[v];
            const int h = v >> 4, cc = v & 15;
            cat[h * 16 + cc] = accO;
        } else {
            g0 += pr_pt[v * 3 + 0]; g1 += pr_pt[v * 3 + 1]; g2 += pr_pt[v * 3 + 2];
            float R[9], ti[3];
            #pragma unroll
            for (int x = 0; x < 9; x++) R[x] = t_rots[i * 9 + x];
            #pragma unroll
            for (int x = 0; x < 3; x++) ti[x] = t_trans[i * 3 + x];
            g0 -= ti[0]; g1 -= ti[1]; g2 -= ti[2];
            float l0 = R[0] * g0 + R[3] * g1 + R[6] * g2;
            float l1 = R[1] * g0 + R[4] * g1 + R[7] * g2;
            float l2 = R[2] * g0 + R[5] * g1 + R[8] * g2;
            float nrm = sqrtf(l0 * l0 + l1 * l1 + l2 * l2 + 1e-8f);
            const int h = v >> 3, p = v & 7;
            int e = h * PV + p;
            cat[192 + e] = l0;
            cat[288 + e] = l1;
            cat[384 + e] = l2;
            cat[480 + e] = nrm;
        }
    }
}

// ---------------- kernel 6: out partials = cat @ Wout k-chunk (no atomics) ----------------
// grid (32 row-tiles, 16 k-chunks of 132); partials to OFF_A (dead after finish).
__global__ __launch_bounds__(384, 4) void out_kernel(
    const float* __restrict__ Wout, const float* __restrict__ ws_c,
    float* __restrict__ ws)
{
    const int rt = blockIdx.x;
    const int kc = blockIdx.y;
    const int t = threadIdx.x;
    __shared__ float ct[16 * 132];
    for (int idx = t * 4; idx < 16 * 132; idx += 384 * 4) {
        int rr = idx / 132, kk = idx % 132;
        *(float4*)&ct[idx] =
            *(const float4*)&ws_c[OFF_CAT + (size_t)(rt * 16 + rr) * 2112 + kc * 132 + kk];
    }
    __syncthreads();
    const int cq = t % 96, rg = t / 96;
    const int c0 = cq * 4;
    float acc[4][4] = {};
    const float* Wp = Wout + (size_t)kc * 132 * 384 + c0;
    #pragma unroll 4
    for (int kk = 0; kk < 132; kk += 4) {
        float4 w0 = *(const float4*)&Wp[(size_t)(kk + 0) * 384];
        float4 w1 = *(const float4*)&Wp[(size_t)(kk + 1) * 384];
        float4 w2 = *(const float4*)&Wp[(size_t)(kk + 2) * 384];
        float4 w3 = *(const float4*)&Wp[(size_t)(kk + 3) * 384];
        #pragma unroll
        for (int r = 0; r < 4; r++) {
            float4 sv = *(const float4*)&ct[(rg * 4 + r) * 132 + kk];
            acc[r][0] += sv.x * w0.x + sv.y * w1.x + sv.z * w2.x + sv.w * w3.x;
            acc[r][1] += sv.x * w0.y + sv.y * w1.y + sv.z * w2.y + sv.w * w3.y;
            acc[r][2] += sv.x * w0.z + sv.y * w1.z + sv.z * w2.z + sv.w * w3.z;
            acc[r][3] += sv.x * w0.w + sv.y * w1.w + sv.z * w2.w + sv.w * w3.w;
        }
    }
    float* dst = ws + OFF_A + (size_t)kc * (512 * 384);
    #pragma unroll
    for (int r = 0; r < 4; r++) {
        float4 a4 = make_float4(acc[r][0], acc[r][1], acc[r][2], acc[r][3]);
        *(float4*)&dst[(size_t)(rt * 16 + rg * 4 + r) * 384 + c0] = a4;
    }
}

// ---------------- kernel 7: out = bias + sum of 16 partials ----------------
__global__ __launch_bounds__(256) void reduce_out_kernel(
    const float* __restrict__ bout, const float* __restrict__ ws,
    float* __restrict__ out)
{
    const int idx = (blockIdx.x * 256 + threadIdx.x) * 4;   // float offset, < 512*384
    const int col = idx % 384;
    float4 acc = *(const float4*)&bout[col];
    #pragma unroll
    for (int kc = 0; kc < 16; kc++) {
        float4 p = *(const float4*)&ws[OFF_A + (size_t)kc * (512 * 384) + idx];
        acc.x += p.x; acc.y += p.y; acc.z += p.z; acc.w += p.w;
    }
    *(float4*)&out[idx] = acc;
}

extern "C" void kernel_launch(void* const* d_in, const int* in_sizes, int n_in,
                              void* d_out, int out_size, void* d_ws, size_t ws_size,
                              hipStream_t stream) {
    const float* s       = (const float*)d_in[0];
    const float* z       = (const float*)d_in[1];
    const float* t_trans = (const float*)d_in[2];
    const float* t_rots  = (const float*)d_in[3];
    const float* mask    = (const float*)d_in[4];
    const float* Wq      = (const float*)d_in[5];
    const float* bq      = (const float*)d_in[6];
    const float* Wkv     = (const float*)d_in[7];
    const float* bkv     = (const float*)d_in[8];
    const float* Wqp     = (const float*)d_in[9];
    const float* bqp     = (const float*)d_in[10];
    const float* Wkvp    = (const float*)d_in[11];
    const float* bkvp    = (const float*)d_in[12];
    const float* Wb      = (const float*)d_in[13];
    const float* bb      = (const float*)d_in[14];
    const float* hweights= (const float*)d_in[15];
    const float* Wout    = (const float*)d_in[16];
    const float* bout    = (const float*)d_in[17];
    float* ws  = (float*)d_ws;
    float* out = (float*)d_out;

    proj_kernel<<<dim3(32, 9), 256, 0, stream>>>(s, Wq, bq, Wkv, bkv, Wqp, bqp, Wkvp, bkvp, ws);
    point_kernel<<<512, 192, 0, stream>>>(t_trans, t_rots, ws);
    logitA_kernel<<<dim3(32, 32), 192, 0, stream>>>(mask, hweights, ws);
    bsoft_kernel<<<512, 512, 0, stream>>>(z, Wb, bb, ws);
    finish_kernel<<<512, 960, 0, stream>>>(z, t_trans, t_rots, ws, ws);
    out_kernel<<<dim3(32, 16), 384, 0, stream>>>(Wout, ws, ws);
    reduce_out_kernel<<<192, 256, 0, stream>>>(bout, ws, out);
}